// Round 11
// baseline (3151.350 us; speedup 1.0000x reference)
//
#include <hip/hip_runtime.h>

// ---------------------------------------------------------------------------
// XFeat detector: fp64-accumulation direct convs (fp32 storage).
// r11: retile 3x3 convs CPT=8, P=2 (fewer loads/cvts per FMA, smaller reg
// state -> 6 waves/SIMD). Accumulation order identical -> bit-exact scores.
// Output (fp32): [kp 4*4096*2 | sc 4*4096 | d 4*4096*64]
// Layout A (ws>=59.2MB, peak 59.03MB) / B (proven-safe peak 57,443,072 B).
// ---------------------------------------------------------------------------

#define EPS_BN 1e-5f

// ------------------------------ zero fill ----------------------------------
__global__ void zero_k(float4* __restrict__ p, size_t n)
{
    for (size_t i = (size_t)blockIdx.x * 256 + threadIdx.x; i < n;
         i += (size_t)gridDim.x * 256)
        p[i] = make_float4(0.f, 0.f, 0.f, 0.f);
}

// ---------- 3x3 conv, BOUNDS-CHECKED input (unpadded), fp64 acc ------------
template<int CIN,int COUT,int CPT,int CHUNK,int HOUT,int STRIDE,int TY,int P,
         int RELU,int BN,int PADOUT>
__global__ __launch_bounds__(HOUT*TY, 6)
void conv3x3b_k(const float* __restrict__ in, const float* __restrict__ wgt,
                const float* __restrict__ cbias, const float* __restrict__ gg,
                const float* __restrict__ bb, float* __restrict__ out)
{
    constexpr int HIN = HOUT * STRIDE;
    constexpr int NG  = COUT / CPT;
    constexpr int YB  = HOUT / (TY * P);
    constexpr int BLK = HOUT * TY;
    constexpr int NR  = (P - 1) * STRIDE + 3;
    static_assert(CIN % CHUNK == 0, "chunk");

    __shared__ double wl[CPT * CHUNK * 9];

    int bid = blockIdx.x;
    int yb  = bid % YB;  int r2 = bid / YB;
    int cog = r2 % NG;   int b  = r2 / NG;
    int tid = threadIdx.x;
    int x   = tid % HOUT;
    int ty  = tid / HOUT;
    int yo0 = (yb * TY + ty) * P;
    int cobase = cog * CPT;

    int xoff[3]; bool okx[3];
#pragma unroll
    for (int kx = 0; kx < 3; kx++) {
        int xi = STRIDE * x - 1 + kx;
        okx[kx]  = (xi >= 0) && (xi < HIN);
        xoff[kx] = min(max(xi, 0), HIN - 1);
    }
    int yoff[NR]; bool oky[NR];
#pragma unroll
    for (int r = 0; r < NR; r++) {
        int yi = STRIDE * yo0 - 1 + r;
        oky[r]  = (yi >= 0) && (yi < HIN);
        yoff[r] = min(max(yi, 0), HIN - 1) * HIN;
    }

    double acc[CPT][P];
#pragma unroll
    for (int co = 0; co < CPT; co++)
#pragma unroll
        for (int p = 0; p < P; p++) acc[co][p] = 0.0;

    const float* inb = in + (size_t)b * CIN * HIN * HIN;

    for (int c0 = 0; c0 < CIN; c0 += CHUNK) {
        __syncthreads();
        for (int i = tid; i < CPT * CHUNK * 9; i += BLK) {
            int k  = i % 9;
            int t2 = i / 9;
            int cc = t2 % CHUNK;
            int co = t2 / CHUNK;
            wl[i] = (double)wgt[((size_t)(cobase + co) * CIN + (c0 + cc)) * 9 + k];
        }
        __syncthreads();

        for (int cc = 0; cc < CHUNK; cc++) {
            const float* inp = inb + (size_t)(c0 + cc) * HIN * HIN;
            double v[NR][3];
#pragma unroll
            for (int r = 0; r < NR; r++)
#pragma unroll
                for (int kx = 0; kx < 3; kx++) {
                    float t = inp[yoff[r] + xoff[kx]];
                    v[r][kx] = (oky[r] && okx[kx]) ? (double)t : 0.0;
                }
#pragma unroll
            for (int co = 0; co < CPT; co++) {
                const double* wp = &wl[(co * CHUNK + cc) * 9];
#pragma unroll
                for (int ky = 0; ky < 3; ky++)
#pragma unroll
                    for (int kx = 0; kx < 3; kx++) {
                        double w = wp[ky * 3 + kx];
#pragma unroll
                        for (int p = 0; p < P; p++)
                            acc[co][p] = fma(v[ky + p * STRIDE][kx], w, acc[co][p]);
                    }
            }
        }
    }

    const float SQ = sqrtf(1.0f + EPS_BN);
    constexpr int WOUT = PADOUT ? HOUT + 2 : HOUT;
    size_t plane = (size_t)WOUT * WOUT;
    float* ob = out + ((size_t)b * COUT + cobase) * plane
              + (PADOUT ? ((size_t)(yo0 + 1) * WOUT + x + 1)
                        : ((size_t)yo0 * WOUT + x));
#pragma unroll
    for (int co = 0; co < CPT; co++) {
        float cb = cbias ? cbias[cobase + co] : 0.f;
#pragma unroll
        for (int p = 0; p < P; p++) {
            float a = (float)acc[co][p] + cb;
            float r;
            if (BN) r = gg[cobase + co] * (a / SQ) + bb[cobase + co];
            else    r = a;
            if (RELU) r = fmaxf(r, 0.f);
            ob[(size_t)co * plane + (size_t)p * WOUT] = r;
        }
    }
}

// ---------- 3x3 conv, PADDED input (no bounds), fp64 acc -------------------
template<int CIN,int COUT,int CPT,int CHUNK,int HOUT,int STRIDE,int TY,int P,
         int RELU,int BN,int PADOUT>
__global__ __launch_bounds__(HOUT*TY, 6)
void conv3x3p_k(const float* __restrict__ in, const float* __restrict__ wgt,
                const float* __restrict__ cbias, const float* __restrict__ gg,
                const float* __restrict__ bb, float* __restrict__ out)
{
    constexpr int HIN = HOUT * STRIDE;
    constexpr int PIN = HIN + 2;
    constexpr int NG  = COUT / CPT;
    constexpr int YB  = HOUT / (TY * P);
    constexpr int BLK = HOUT * TY;
    constexpr int NR  = (P - 1) * STRIDE + 3;
    constexpr size_t PIN2 = (size_t)PIN * PIN;
    static_assert(CIN % CHUNK == 0, "chunk");

    __shared__ double wl[CPT * CHUNK * 9];

    int bid = blockIdx.x;
    int yb  = bid % YB;  int r2 = bid / YB;
    int cog = r2 % NG;   int b  = r2 / NG;
    int tid = threadIdx.x;
    int x   = tid % HOUT;
    int ty  = tid / HOUT;
    int yo0 = (yb * TY + ty) * P;
    int cobase = cog * CPT;

    double acc[CPT][P];
#pragma unroll
    for (int co = 0; co < CPT; co++)
#pragma unroll
        for (int p = 0; p < P; p++) acc[co][p] = 0.0;

    const float* inb = in + (size_t)b * CIN * PIN2
                     + (size_t)(STRIDE * yo0) * PIN + STRIDE * x;

    for (int c0 = 0; c0 < CIN; c0 += CHUNK) {
        __syncthreads();
        for (int i = tid; i < CPT * CHUNK * 9; i += BLK) {
            int k  = i % 9;
            int t2 = i / 9;
            int cc = t2 % CHUNK;
            int co = t2 / CHUNK;
            wl[i] = (double)wgt[((size_t)(cobase + co) * CIN + (c0 + cc)) * 9 + k];
        }
        __syncthreads();

        const float* ip = inb + (size_t)c0 * PIN2;
        for (int cc = 0; cc < CHUNK; cc++) {
            double v[NR][3];
#pragma unroll
            for (int r = 0; r < NR; r++)
#pragma unroll
                for (int kx = 0; kx < 3; kx++)
                    v[r][kx] = (double)ip[(size_t)r * PIN + kx];
#pragma unroll
            for (int co = 0; co < CPT; co++) {
                const double* wp = &wl[(co * CHUNK + cc) * 9];
#pragma unroll
                for (int ky = 0; ky < 3; ky++)
#pragma unroll
                    for (int kx = 0; kx < 3; kx++) {
                        double w = wp[ky * 3 + kx];
#pragma unroll
                        for (int p = 0; p < P; p++)
                            acc[co][p] = fma(v[ky + p * STRIDE][kx], w, acc[co][p]);
                    }
            }
            ip += PIN2;
        }
    }

    const float SQ = sqrtf(1.0f + EPS_BN);
    constexpr int WOUT = PADOUT ? HOUT + 2 : HOUT;
    size_t plane = (size_t)WOUT * WOUT;
    float* ob = out + ((size_t)b * COUT + cobase) * plane
              + (PADOUT ? ((size_t)(yo0 + 1) * WOUT + x + 1)
                        : ((size_t)yo0 * WOUT + x));
#pragma unroll
    for (int co = 0; co < CPT; co++) {
        float cb = cbias ? cbias[cobase + co] : 0.f;
#pragma unroll
        for (int p = 0; p < P; p++) {
            float a = (float)acc[co][p] + cb;
            float r;
            if (BN) r = gg[cobase + co] * (a / SQ) + bb[cobase + co];
            else    r = a;
            if (RELU) r = fmaxf(r, 0.f);
            ob[(size_t)co * plane + (size_t)p * WOUT] = r;
        }
    }
}

// ---------------- 1x1 conv (fp64 acc, fp64 LDS weights) --------------------
template<int CIN,int COUT,int CPT,int CHUNK,int TY,int P,int RELU,int BN,int PADOUT>
__global__ __launch_bounds__(96*TY, 4)
void conv1x1p_k(const float* __restrict__ in, const float* __restrict__ wgt,
                const float* __restrict__ cbias, const float* __restrict__ gg,
                const float* __restrict__ bb, float* __restrict__ out,
                int cin_tot, int cin_off)
{
    constexpr int HOUT = 96;
    constexpr int HW   = 96 * 96;
    constexpr int NG   = COUT / CPT;
    constexpr int YB   = HOUT / (TY * P);
    constexpr int BLK  = 96 * TY;

    __shared__ double wl[CPT * CHUNK];

    int bid = blockIdx.x;
    int yb  = bid % YB;  int r2 = bid / YB;
    int cog = r2 % NG;   int b  = r2 / NG;
    int tid = threadIdx.x;
    int x   = tid % HOUT;
    int ty  = tid / HOUT;
    int yo0 = (yb * TY + ty) * P;
    int cobase = cog * CPT;

    double acc[CPT][P];
#pragma unroll
    for (int co = 0; co < CPT; co++)
#pragma unroll
        for (int p = 0; p < P; p++) acc[co][p] = 0.0;

    const float* inb = in + ((size_t)b * cin_tot + cin_off) * HW + (size_t)yo0 * HOUT + x;

    for (int c0 = 0; c0 < CIN; c0 += CHUNK) {
        __syncthreads();
        for (int i = tid; i < CPT * CHUNK; i += BLK) {
            int cc = i % CHUNK;
            int co = i / CHUNK;
            wl[i] = (double)wgt[(size_t)(cobase + co) * CIN + (c0 + cc)];
        }
        __syncthreads();
        for (int cc = 0; cc < CHUNK; cc++) {
            const float* inp = inb + (size_t)(c0 + cc) * HW;
            double v[P];
#pragma unroll
            for (int p = 0; p < P; p++) v[p] = (double)inp[p * HOUT];
#pragma unroll
            for (int co = 0; co < CPT; co++) {
                double w = wl[co * CHUNK + cc];
#pragma unroll
                for (int p = 0; p < P; p++) acc[co][p] = fma(v[p], w, acc[co][p]);
            }
        }
    }

    const float SQ = sqrtf(1.0f + EPS_BN);
    constexpr int WOUT = PADOUT ? 98 : 96;
    size_t plane = (size_t)WOUT * WOUT;
    float* ob = out + ((size_t)b * COUT + cobase) * plane
              + (PADOUT ? ((size_t)(yo0 + 1) * WOUT + x + 1)
                        : ((size_t)yo0 * WOUT + x));
#pragma unroll
    for (int co = 0; co < CPT; co++) {
        float cb = cbias ? cbias[cobase + co] : 0.f;
#pragma unroll
        for (int p = 0; p < P; p++) {
            float a = (float)acc[co][p] + cb;
            float r;
            if (BN) r = gg[cobase + co] * (a / SQ) + bb[cobase + co];
            else    r = a;
            if (RELU) r = fmaxf(r, 0.f);
            ob[(size_t)co * plane + (size_t)p * WOUT] = r;
        }
    }
}

// --------------- pack det/desc head-1 weights into one 64-ch conv ----------
__global__ void pack_head_k(const float* __restrict__ dw, const float* __restrict__ db,
                            const float* __restrict__ dg, const float* __restrict__ dbe,
                            const float* __restrict__ sw, const float* __restrict__ sb,
                            const float* __restrict__ sg, const float* __restrict__ sbe,
                            float* __restrict__ wc, float* __restrict__ cbc,
                            float* __restrict__ gc, float* __restrict__ bec)
{
    int i = blockIdx.x * 256 + threadIdx.x;
    const int WN = 32 * 64 * 9;
    if (i < WN) { wc[i] = dw[i]; wc[WN + i] = sw[i]; }
    if (i < 32) {
        cbc[i] = db[i]; cbc[32 + i] = sb[i];
        gc[i]  = dg[i]; gc[32 + i]  = sg[i];
        bec[i] = dbe[i]; bec[32 + i] = sbe[i];
    }
}

// ------------------------- NMS + sortable key build ------------------------
__global__ void nms_keys_k(const float* __restrict__ score, unsigned long long* __restrict__ keys)
{
    int tid = blockIdx.x * 256 + threadIdx.x;      // 4 * 16384
    int b = tid >> 14;
    int i = tid & 16383;
    unsigned long long key = ~0ULL;                // padding sorts last
    if (i < 9216) {
        int y = i / 96, x = i % 96;
        const float* sb = score + (size_t)b * 9216;
        float s = sb[i];
        float m = -INFINITY;
#pragma unroll
        for (int dy = -2; dy <= 1; dy++) {
            int yy = y + dy;
            if (yy < 0 || yy >= 96) continue;
#pragma unroll
            for (int dx = -2; dx <= 1; dx++) {
                int xx = x + dx;
                if (xx < 0 || xx >= 96) continue;
                m = fmaxf(m, sb[yy * 96 + xx]);
            }
        }
        float nv = (s == m) ? s : 0.0f;
        if (nv == 0.0f) nv = 0.0f;                 // canonicalize -0.0 -> +0.0
        unsigned u = __float_as_uint(nv);
        unsigned sk = (u & 0x80000000u) ? ~u : (u | 0x80000000u);
        key = ((unsigned long long)(~sk) << 32) | (unsigned)i;
    }
    keys[(size_t)b * 16384 + i] = key;
}

// ------------------------- bitonic sort (per batch) ------------------------
__global__ __launch_bounds__(1024) void sort_k(unsigned long long* __restrict__ keys)
{
    __shared__ unsigned long long s[16384];
    unsigned long long* kb = keys + (size_t)blockIdx.x * 16384;
    for (int i = threadIdx.x; i < 16384; i += 1024) s[i] = kb[i];
    __syncthreads();
    for (int k = 2; k <= 16384; k <<= 1) {
        for (int j = k >> 1; j > 0; j >>= 1) {
            for (int i = threadIdx.x; i < 16384; i += 1024) {
                int ixj = i ^ j;
                if (ixj > i) {
                    unsigned long long a = s[i], c = s[ixj];
                    bool up = ((i & k) == 0);
                    if ((a > c) == up) { s[i] = c; s[ixj] = a; }
                }
            }
            __syncthreads();
        }
    }
    for (int i = threadIdx.x; i < 16384; i += 1024) kb[i] = s[i];
}

// ------------------------- emit keypoints + scores (fp32) ------------------
__global__ void emit_k(const unsigned long long* __restrict__ keys,
                       float* __restrict__ kp, float* __restrict__ sc)
{
    int tid = blockIdx.x * 256 + threadIdx.x;      // 4 * 4096
    int b = tid >> 12;
    int r = tid & 4095;
    unsigned long long key = keys[(size_t)b * 16384 + r];
    unsigned idx = (unsigned)(key & 0xFFFFFFFFu);
    unsigned hi  = (unsigned)(key >> 32);
    unsigned sk  = ~hi;
    unsigned u   = (sk & 0x80000000u) ? (sk ^ 0x80000000u) : ~sk;
    float val = __uint_as_float(u);
    float tx = (float)(idx % 96);
    float ty = (float)(idx / 96);
    kp[(size_t)tid * 2 + 0] = tx;
    kp[(size_t)tid * 2 + 1] = ty;
    sc[tid] = val;
}

// --------------------- descriptor gather + L2 normalize (fp32) -------------
__global__ __launch_bounds__(256) void desc_out_k(const unsigned long long* __restrict__ keys,
                                                  const float* __restrict__ dm,
                                                  float* __restrict__ outd)
{
    int warp = threadIdx.x >> 6, lane = threadIdx.x & 63;
    int kpid = blockIdx.x * 4 + warp;              // 0..16383
    int b = kpid >> 12, r = kpid & 4095;
    unsigned long long key = keys[(size_t)b * 16384 + r];
    int idx = (int)(unsigned)(key & 0xFFFFFFFFu);
    float v = dm[((size_t)b * 64 + lane) * 9216 + idx];
    float ss = v * v;
#pragma unroll
    for (int o = 32; o > 0; o >>= 1) ss += __shfl_xor(ss, o, 64);
    float n = fmaxf(sqrtf(ss), 1e-12f);
    outd[(size_t)kpid * 64 + lane] = v / n;
}

// ---------------------------------------------------------------------------
extern "C" void kernel_launch(void* const* d_in, const int* in_sizes, int n_in,
                              void* d_out, int out_size, void* d_ws, size_t ws_size,
                              hipStream_t stream)
{
    const float* x      = (const float*)d_in[0];
    const float* w1     = (const float*)d_in[1];
    const float* g1     = (const float*)d_in[2];
    const float* b1     = (const float*)d_in[3];
    const float* w2     = (const float*)d_in[4];
    const float* g2     = (const float*)d_in[5];
    const float* b2     = (const float*)d_in[6];
    const float* w3     = (const float*)d_in[7];
    const float* g3     = (const float*)d_in[8];
    const float* b3     = (const float*)d_in[9];
    const float* w4     = (const float*)d_in[10];
    const float* g4     = (const float*)d_in[11];
    const float* b4     = (const float*)d_in[12];
    const float* wf     = (const float*)d_in[13];
    const float* bf     = (const float*)d_in[14];
    const float* det_w1 = (const float*)d_in[15];
    const float* det_b1 = (const float*)d_in[16];
    const float* det_g  = (const float*)d_in[17];
    const float* det_be = (const float*)d_in[18];
    const float* det_w2 = (const float*)d_in[19];
    const float* det_b2 = (const float*)d_in[20];
    const float* ds_w1  = (const float*)d_in[21];
    const float* ds_b1  = (const float*)d_in[22];
    const float* ds_g1  = (const float*)d_in[23];
    const float* ds_be1 = (const float*)d_in[24];
    const float* ds_w2  = (const float*)d_in[25];
    const float* ds_b2  = (const float*)d_in[26];
    const float* ds_g2  = (const float*)d_in[27];
    const float* ds_be2 = (const float*)d_in[28];

    char* ws = (char*)d_ws;
    // ---- misc persistent buffers at base [0, 819,968) ----
    float* scorem = (float*)(ws + 0);                              // [4,9216]
    unsigned long long* keys = (unsigned long long*)(ws + 147456); // [4,16384]
    float* wc  = (float*)(ws + 671744);                            // [64,64,9]
    float* pc  = (float*)(ws + 819200);                            // 768 B
    float* cbc = pc, *gc = pc + 64, *bec = pc + 128;
    const size_t B0 = 819968;

    pack_head_k<<<72, 256, 0, stream>>>(det_w1, det_b1, det_g, det_be,
                                        ds_w1, ds_b1, ds_g1, ds_be1,
                                        wc, cbc, gc, bec);

    float* desc_full;

    if (ws_size >= 59200000ull) {
        // =============== Layout A (peak 59,028,224 B) ======================
        float* c1pb  = (float*)(ws + B0);           // [32,386,386]   (phase 1)
        float* c2p   = (float*)(ws + 20488960);     // [4,64,194,194]
        float* c3p   = (float*)(ws + B0);           // [4,128,98,98]  (phase 2)
        float* c4    = (float*)(ws + 20488960);     // [4,256,96,96]  (phase 3)
        float* featp = (float*)(ws + B0);           // [4,64,98,98]   (phase 4)
        float* dd1   = (float*)(ws + 10654464);     // [4,64,96,96]
        desc_full    = (float*)(ws + 20488960);     // [4,64,96,96]

        zero_k<<<2048, 256, 0, stream>>>((float4*)(ws + B0), 3638016);

        for (int b = 0; b < 4; b++) {
            conv3x3b_k<3, 32, 8, 3, 384, 2, 1, 2, 1, 1, 1><<<192 * 4, 384, 0, stream>>>(
                x + (size_t)b * 3 * 768 * 768, w1, nullptr, g1, b1, c1pb);
            conv3x3p_k<32, 64, 8, 32, 192, 2, 1, 2, 1, 1, 1><<<96 * 8, 192, 0, stream>>>(
                c1pb, w2, nullptr, g2, b2, c2p + (size_t)b * 2408704);
        }
        zero_k<<<2048, 256, 0, stream>>>((float4*)(ws + B0), 1229312);
        conv3x3p_k<64, 128, 8, 32, 96, 2, 2, 2, 1, 1, 1><<<24 * 16 * 4, 192, 0, stream>>>(
            c2p, w3, nullptr, g3, b3, c3p);
        conv3x3p_k<128, 256, 8, 32, 96, 1, 2, 2, 1, 1, 0><<<24 * 32 * 4, 192, 0, stream>>>(
            c3p, w4, nullptr, g4, b4, c4);
        zero_k<<<2048, 256, 0, stream>>>((float4*)(ws + B0), 614656);
        conv1x1p_k<256, 64, 8, 64, 2, 4, 0, 0, 1><<<12 * 8 * 4, 192, 0, stream>>>(
            c4, wf, bf, nullptr, nullptr, featp, 256, 0);
        conv3x3p_k<64, 64, 8, 32, 96, 1, 2, 2, 1, 1, 0><<<24 * 8 * 4, 192, 0, stream>>>(
            featp, wc, cbc, gc, bec, dd1);
        conv1x1p_k<32, 1, 1, 32, 2, 4, 0, 0, 0><<<12 * 1 * 4, 192, 0, stream>>>(
            dd1, det_w2, det_b2, nullptr, nullptr, scorem, 64, 0);
        conv1x1p_k<32, 64, 8, 32, 2, 4, 0, 1, 0><<<12 * 8 * 4, 192, 0, stream>>>(
            dd1, ds_w2, ds_b2, ds_g2, ds_be2, desc_full, 64, 32);
    } else {
        // =============== Layout B (peak 57,443,072 B, proven) ==============
        float* c3    = (float*)(ws + B0);           // [4,128,96,96] unpadded
        float* c1pb  = (float*)(ws + 19694336);     // [32,386,386]
        float* c2pb  = (float*)(ws + 38765824);     // [64,194,194]
        float* c4    = (float*)(ws + 19694336);     // [4,256,96,96]
        float* featp = (float*)(ws + B0);           // [4,64,98,98]
        float* dd1   = (float*)(ws + 10654464);     // [4,64,96,96]
        desc_full    = (float*)(ws + 20091648);     // [4,64,96,96]

        zero_k<<<2048, 256, 0, stream>>>((float4*)(ws + B0), 2973792);

        for (int b = 0; b < 4; b++) {
            conv3x3b_k<3, 32, 8, 3, 384, 2, 1, 2, 1, 1, 1><<<192 * 4, 384, 0, stream>>>(
                x + (size_t)b * 3 * 768 * 768, w1, nullptr, g1, b1, c1pb);
            conv3x3p_k<32, 64, 8, 32, 192, 2, 1, 2, 1, 1, 1><<<96 * 8, 192, 0, stream>>>(
                c1pb, w2, nullptr, g2, b2, c2pb);
            conv3x3p_k<64, 128, 8, 32, 96, 2, 2, 2, 1, 1, 0><<<24 * 16, 192, 0, stream>>>(
                c2pb, w3, nullptr, g3, b3, c3 + (size_t)b * 1179648);
        }
        conv3x3b_k<128, 256, 8, 32, 96, 1, 2, 2, 1, 1, 0><<<24 * 32 * 4, 192, 0, stream>>>(
            c3, w4, nullptr, g4, b4, c4);
        zero_k<<<2048, 256, 0, stream>>>((float4*)(ws + B0), 614656);
        conv1x1p_k<256, 64, 8, 64, 2, 4, 0, 0, 1><<<12 * 8 * 4, 192, 0, stream>>>(
            c4, wf, bf, nullptr, nullptr, featp, 256, 0);
        conv3x3p_k<64, 64, 8, 32, 96, 1, 2, 2, 1, 1, 0><<<24 * 8 * 4, 192, 0, stream>>>(
            featp, wc, cbc, gc, bec, dd1);
        conv1x1p_k<32, 1, 1, 32, 2, 4, 0, 0, 0><<<12 * 1 * 4, 192, 0, stream>>>(
            dd1, det_w2, det_b2, nullptr, nullptr, scorem, 64, 0);
        conv1x1p_k<32, 64, 8, 32, 2, 4, 0, 1, 0><<<12 * 8 * 4, 192, 0, stream>>>(
            dd1, ds_w2, ds_b2, ds_g2, ds_be2, desc_full, 64, 32);
    }

    nms_keys_k<<<256, 256, 0, stream>>>(scorem, keys);
    sort_k<<<4, 1024, 0, stream>>>(keys);

    float* out_kp = (float*)d_out;
    float* out_sc = out_kp + 4 * 4096 * 2;
    float* out_d  = out_sc + 4 * 4096;
    emit_k<<<64, 256, 0, stream>>>(keys, out_kp, out_sc);
    desc_out_k<<<4096, 256, 0, stream>>>(keys, desc_full, out_d);
}

// Round 12
// 2217.074 us; speedup vs baseline: 1.4214x; 1.4214x over previous
//
#include <hip/hip_runtime.h>

// ---------------------------------------------------------------------------
// XFeat detector: fp64-accumulation direct convs (fp32 storage).
// r12 = r10 tiling (CPT=4, P=4, CHUNK=32 — proven best) + manual in-chunk
// input prefetch (loads only; FMA order identical -> bit-exact scores).
// Output (fp32): [kp 4*4096*2 | sc 4*4096 | d 4*4096*64]
// Layout A (ws>=59.2MB, peak 59.03MB — PROVEN ACTIVE in r11 profile) /
// Layout B fallback (peak 57,443,072 B).
// ---------------------------------------------------------------------------

#define EPS_BN 1e-5f

// ------------------------------ zero fill ----------------------------------
__global__ void zero_k(float4* __restrict__ p, size_t n)
{
    for (size_t i = (size_t)blockIdx.x * 256 + threadIdx.x; i < n;
         i += (size_t)gridDim.x * 256)
        p[i] = make_float4(0.f, 0.f, 0.f, 0.f);
}

// ---------- 3x3 conv, BOUNDS-CHECKED input (unpadded), fp64 acc ------------
template<int CIN,int COUT,int CPT,int CHUNK,int HOUT,int STRIDE,int TY,int P,
         int RELU,int BN,int PADOUT>
__global__ __launch_bounds__(HOUT*TY, 4)
void conv3x3b_k(const float* __restrict__ in, const float* __restrict__ wgt,
                const float* __restrict__ cbias, const float* __restrict__ gg,
                const float* __restrict__ bb, float* __restrict__ out)
{
    constexpr int HIN = HOUT * STRIDE;
    constexpr int NG  = COUT / CPT;
    constexpr int YB  = HOUT / (TY * P);
    constexpr int BLK = HOUT * TY;
    constexpr int NR  = (P - 1) * STRIDE + 3;
    static_assert(CIN % CHUNK == 0, "chunk");

    __shared__ double wl[CPT * CHUNK * 9];

    int bid = blockIdx.x;
    int yb  = bid % YB;  int r2 = bid / YB;
    int cog = r2 % NG;   int b  = r2 / NG;
    int tid = threadIdx.x;
    int x   = tid % HOUT;
    int ty  = tid / HOUT;
    int yo0 = (yb * TY + ty) * P;
    int cobase = cog * CPT;

    int xoff[3]; bool okx[3];
#pragma unroll
    for (int kx = 0; kx < 3; kx++) {
        int xi = STRIDE * x - 1 + kx;
        okx[kx]  = (xi >= 0) && (xi < HIN);
        xoff[kx] = min(max(xi, 0), HIN - 1);
    }
    int yoff[NR]; bool oky[NR];
#pragma unroll
    for (int r = 0; r < NR; r++) {
        int yi = STRIDE * yo0 - 1 + r;
        oky[r]  = (yi >= 0) && (yi < HIN);
        yoff[r] = min(max(yi, 0), HIN - 1) * HIN;
    }

    double acc[CPT][P];
#pragma unroll
    for (int co = 0; co < CPT; co++)
#pragma unroll
        for (int p = 0; p < P; p++) acc[co][p] = 0.0;

    const float* inb = in + (size_t)b * CIN * HIN * HIN;

    for (int c0 = 0; c0 < CIN; c0 += CHUNK) {
        __syncthreads();
        for (int i = tid; i < CPT * CHUNK * 9; i += BLK) {
            int k  = i % 9;
            int t2 = i / 9;
            int cc = t2 % CHUNK;
            int co = t2 / CHUNK;
            wl[i] = (double)wgt[((size_t)(cobase + co) * CIN + (c0 + cc)) * 9 + k];
        }
        __syncthreads();

        // prefetch cc=0
        float f[NR][3];
        {
            const float* inp = inb + (size_t)c0 * HIN * HIN;
#pragma unroll
            for (int r = 0; r < NR; r++)
#pragma unroll
                for (int kx = 0; kx < 3; kx++)
                    f[r][kx] = inp[yoff[r] + xoff[kx]];
        }
        for (int cc = 0; cc < CHUNK; cc++) {
            float fn[NR][3];
            if (cc + 1 < CHUNK) {
                const float* inp = inb + (size_t)(c0 + cc + 1) * HIN * HIN;
#pragma unroll
                for (int r = 0; r < NR; r++)
#pragma unroll
                    for (int kx = 0; kx < 3; kx++)
                        fn[r][kx] = inp[yoff[r] + xoff[kx]];
            }
            double v[NR][3];
#pragma unroll
            for (int r = 0; r < NR; r++)
#pragma unroll
                for (int kx = 0; kx < 3; kx++)
                    v[r][kx] = (oky[r] && okx[kx]) ? (double)f[r][kx] : 0.0;
#pragma unroll
            for (int co = 0; co < CPT; co++) {
                const double* wp = &wl[(co * CHUNK + cc) * 9];
#pragma unroll
                for (int ky = 0; ky < 3; ky++)
#pragma unroll
                    for (int kx = 0; kx < 3; kx++) {
                        double w = wp[ky * 3 + kx];
#pragma unroll
                        for (int p = 0; p < P; p++)
                            acc[co][p] = fma(v[ky + p * STRIDE][kx], w, acc[co][p]);
                    }
            }
            if (cc + 1 < CHUNK) {
#pragma unroll
                for (int r = 0; r < NR; r++)
#pragma unroll
                    for (int kx = 0; kx < 3; kx++)
                        f[r][kx] = fn[r][kx];
            }
        }
    }

    const float SQ = sqrtf(1.0f + EPS_BN);
    constexpr int WOUT = PADOUT ? HOUT + 2 : HOUT;
    size_t plane = (size_t)WOUT * WOUT;
    float* ob = out + ((size_t)b * COUT + cobase) * plane
              + (PADOUT ? ((size_t)(yo0 + 1) * WOUT + x + 1)
                        : ((size_t)yo0 * WOUT + x));
#pragma unroll
    for (int co = 0; co < CPT; co++) {
        float cb = cbias ? cbias[cobase + co] : 0.f;
#pragma unroll
        for (int p = 0; p < P; p++) {
            float a = (float)acc[co][p] + cb;
            float r;
            if (BN) r = gg[cobase + co] * (a / SQ) + bb[cobase + co];
            else    r = a;
            if (RELU) r = fmaxf(r, 0.f);
            ob[(size_t)co * plane + (size_t)p * WOUT] = r;
        }
    }
}

// ---------- 3x3 conv, PADDED input (no bounds), fp64 acc -------------------
template<int CIN,int COUT,int CPT,int CHUNK,int HOUT,int STRIDE,int TY,int P,
         int RELU,int BN,int PADOUT>
__global__ __launch_bounds__(HOUT*TY, 4)
void conv3x3p_k(const float* __restrict__ in, const float* __restrict__ wgt,
                const float* __restrict__ cbias, const float* __restrict__ gg,
                const float* __restrict__ bb, float* __restrict__ out)
{
    constexpr int HIN = HOUT * STRIDE;
    constexpr int PIN = HIN + 2;
    constexpr int NG  = COUT / CPT;
    constexpr int YB  = HOUT / (TY * P);
    constexpr int BLK = HOUT * TY;
    constexpr int NR  = (P - 1) * STRIDE + 3;
    constexpr size_t PIN2 = (size_t)PIN * PIN;
    static_assert(CIN % CHUNK == 0, "chunk");

    __shared__ double wl[CPT * CHUNK * 9];

    int bid = blockIdx.x;
    int yb  = bid % YB;  int r2 = bid / YB;
    int cog = r2 % NG;   int b  = r2 / NG;
    int tid = threadIdx.x;
    int x   = tid % HOUT;
    int ty  = tid / HOUT;
    int yo0 = (yb * TY + ty) * P;
    int cobase = cog * CPT;

    double acc[CPT][P];
#pragma unroll
    for (int co = 0; co < CPT; co++)
#pragma unroll
        for (int p = 0; p < P; p++) acc[co][p] = 0.0;

    const float* inb = in + (size_t)b * CIN * PIN2
                     + (size_t)(STRIDE * yo0) * PIN + STRIDE * x;

    for (int c0 = 0; c0 < CIN; c0 += CHUNK) {
        __syncthreads();
        for (int i = tid; i < CPT * CHUNK * 9; i += BLK) {
            int k  = i % 9;
            int t2 = i / 9;
            int cc = t2 % CHUNK;
            int co = t2 / CHUNK;
            wl[i] = (double)wgt[((size_t)(cobase + co) * CIN + (c0 + cc)) * 9 + k];
        }
        __syncthreads();

        const float* ip = inb + (size_t)c0 * PIN2;
        // prefetch cc=0
        float f[NR][3];
#pragma unroll
        for (int r = 0; r < NR; r++)
#pragma unroll
            for (int kx = 0; kx < 3; kx++)
                f[r][kx] = ip[(size_t)r * PIN + kx];

        for (int cc = 0; cc < CHUNK; cc++) {
            float fn[NR][3];
            if (cc + 1 < CHUNK) {
                const float* ipn = ip + PIN2;
#pragma unroll
                for (int r = 0; r < NR; r++)
#pragma unroll
                    for (int kx = 0; kx < 3; kx++)
                        fn[r][kx] = ipn[(size_t)r * PIN + kx];
            }
            double v[NR][3];
#pragma unroll
            for (int r = 0; r < NR; r++)
#pragma unroll
                for (int kx = 0; kx < 3; kx++)
                    v[r][kx] = (double)f[r][kx];
#pragma unroll
            for (int co = 0; co < CPT; co++) {
                const double* wp = &wl[(co * CHUNK + cc) * 9];
#pragma unroll
                for (int ky = 0; ky < 3; ky++)
#pragma unroll
                    for (int kx = 0; kx < 3; kx++) {
                        double w = wp[ky * 3 + kx];
#pragma unroll
                        for (int p = 0; p < P; p++)
                            acc[co][p] = fma(v[ky + p * STRIDE][kx], w, acc[co][p]);
                    }
            }
            if (cc + 1 < CHUNK) {
#pragma unroll
                for (int r = 0; r < NR; r++)
#pragma unroll
                    for (int kx = 0; kx < 3; kx++)
                        f[r][kx] = fn[r][kx];
            }
            ip += PIN2;
        }
    }

    const float SQ = sqrtf(1.0f + EPS_BN);
    constexpr int WOUT = PADOUT ? HOUT + 2 : HOUT;
    size_t plane = (size_t)WOUT * WOUT;
    float* ob = out + ((size_t)b * COUT + cobase) * plane
              + (PADOUT ? ((size_t)(yo0 + 1) * WOUT + x + 1)
                        : ((size_t)yo0 * WOUT + x));
#pragma unroll
    for (int co = 0; co < CPT; co++) {
        float cb = cbias ? cbias[cobase + co] : 0.f;
#pragma unroll
        for (int p = 0; p < P; p++) {
            float a = (float)acc[co][p] + cb;
            float r;
            if (BN) r = gg[cobase + co] * (a / SQ) + bb[cobase + co];
            else    r = a;
            if (RELU) r = fmaxf(r, 0.f);
            ob[(size_t)co * plane + (size_t)p * WOUT] = r;
        }
    }
}

// ---------------- 1x1 conv (fp64 acc, fp64 LDS weights) --------------------
template<int CIN,int COUT,int CPT,int CHUNK,int TY,int P,int RELU,int BN,int PADOUT>
__global__ __launch_bounds__(96*TY, 4)
void conv1x1p_k(const float* __restrict__ in, const float* __restrict__ wgt,
                const float* __restrict__ cbias, const float* __restrict__ gg,
                const float* __restrict__ bb, float* __restrict__ out,
                int cin_tot, int cin_off)
{
    constexpr int HOUT = 96;
    constexpr int HW   = 96 * 96;
    constexpr int NG   = COUT / CPT;
    constexpr int YB   = HOUT / (TY * P);
    constexpr int BLK  = 96 * TY;

    __shared__ double wl[CPT * CHUNK];

    int bid = blockIdx.x;
    int yb  = bid % YB;  int r2 = bid / YB;
    int cog = r2 % NG;   int b  = r2 / NG;
    int tid = threadIdx.x;
    int x   = tid % HOUT;
    int ty  = tid / HOUT;
    int yo0 = (yb * TY + ty) * P;
    int cobase = cog * CPT;

    double acc[CPT][P];
#pragma unroll
    for (int co = 0; co < CPT; co++)
#pragma unroll
        for (int p = 0; p < P; p++) acc[co][p] = 0.0;

    const float* inb = in + ((size_t)b * cin_tot + cin_off) * HW + (size_t)yo0 * HOUT + x;

    for (int c0 = 0; c0 < CIN; c0 += CHUNK) {
        __syncthreads();
        for (int i = tid; i < CPT * CHUNK; i += BLK) {
            int cc = i % CHUNK;
            int co = i / CHUNK;
            wl[i] = (double)wgt[(size_t)(cobase + co) * CIN + (c0 + cc)];
        }
        __syncthreads();
        for (int cc = 0; cc < CHUNK; cc++) {
            const float* inp = inb + (size_t)(c0 + cc) * HW;
            double v[P];
#pragma unroll
            for (int p = 0; p < P; p++) v[p] = (double)inp[p * HOUT];
#pragma unroll
            for (int co = 0; co < CPT; co++) {
                double w = wl[co * CHUNK + cc];
#pragma unroll
                for (int p = 0; p < P; p++) acc[co][p] = fma(v[p], w, acc[co][p]);
            }
        }
    }

    const float SQ = sqrtf(1.0f + EPS_BN);
    constexpr int WOUT = PADOUT ? 98 : 96;
    size_t plane = (size_t)WOUT * WOUT;
    float* ob = out + ((size_t)b * COUT + cobase) * plane
              + (PADOUT ? ((size_t)(yo0 + 1) * WOUT + x + 1)
                        : ((size_t)yo0 * WOUT + x));
#pragma unroll
    for (int co = 0; co < CPT; co++) {
        float cb = cbias ? cbias[cobase + co] : 0.f;
#pragma unroll
        for (int p = 0; p < P; p++) {
            float a = (float)acc[co][p] + cb;
            float r;
            if (BN) r = gg[cobase + co] * (a / SQ) + bb[cobase + co];
            else    r = a;
            if (RELU) r = fmaxf(r, 0.f);
            ob[(size_t)co * plane + (size_t)p * WOUT] = r;
        }
    }
}

// --------------- pack det/desc head-1 weights into one 64-ch conv ----------
__global__ void pack_head_k(const float* __restrict__ dw, const float* __restrict__ db,
                            const float* __restrict__ dg, const float* __restrict__ dbe,
                            const float* __restrict__ sw, const float* __restrict__ sb,
                            const float* __restrict__ sg, const float* __restrict__ sbe,
                            float* __restrict__ wc, float* __restrict__ cbc,
                            float* __restrict__ gc, float* __restrict__ bec)
{
    int i = blockIdx.x * 256 + threadIdx.x;
    const int WN = 32 * 64 * 9;
    if (i < WN) { wc[i] = dw[i]; wc[WN + i] = sw[i]; }
    if (i < 32) {
        cbc[i] = db[i]; cbc[32 + i] = sb[i];
        gc[i]  = dg[i]; gc[32 + i]  = sg[i];
        bec[i] = dbe[i]; bec[32 + i] = sbe[i];
    }
}

// ------------------------- NMS + sortable key build ------------------------
__global__ void nms_keys_k(const float* __restrict__ score, unsigned long long* __restrict__ keys)
{
    int tid = blockIdx.x * 256 + threadIdx.x;      // 4 * 16384
    int b = tid >> 14;
    int i = tid & 16383;
    unsigned long long key = ~0ULL;                // padding sorts last
    if (i < 9216) {
        int y = i / 96, x = i % 96;
        const float* sb = score + (size_t)b * 9216;
        float s = sb[i];
        float m = -INFINITY;
#pragma unroll
        for (int dy = -2; dy <= 1; dy++) {
            int yy = y + dy;
            if (yy < 0 || yy >= 96) continue;
#pragma unroll
            for (int dx = -2; dx <= 1; dx++) {
                int xx = x + dx;
                if (xx < 0 || xx >= 96) continue;
                m = fmaxf(m, sb[yy * 96 + xx]);
            }
        }
        float nv = (s == m) ? s : 0.0f;
        if (nv == 0.0f) nv = 0.0f;                 // canonicalize -0.0 -> +0.0
        unsigned u = __float_as_uint(nv);
        unsigned sk = (u & 0x80000000u) ? ~u : (u | 0x80000000u);
        key = ((unsigned long long)(~sk) << 32) | (unsigned)i;
    }
    keys[(size_t)b * 16384 + i] = key;
}

// ------------------------- bitonic sort (per batch) ------------------------
__global__ __launch_bounds__(1024) void sort_k(unsigned long long* __restrict__ keys)
{
    __shared__ unsigned long long s[16384];
    unsigned long long* kb = keys + (size_t)blockIdx.x * 16384;
    for (int i = threadIdx.x; i < 16384; i += 1024) s[i] = kb[i];
    __syncthreads();
    for (int k = 2; k <= 16384; k <<= 1) {
        for (int j = k >> 1; j > 0; j >>= 1) {
            for (int i = threadIdx.x; i < 16384; i += 1024) {
                int ixj = i ^ j;
                if (ixj > i) {
                    unsigned long long a = s[i], c = s[ixj];
                    bool up = ((i & k) == 0);
                    if ((a > c) == up) { s[i] = c; s[ixj] = a; }
                }
            }
            __syncthreads();
        }
    }
    for (int i = threadIdx.x; i < 16384; i += 1024) kb[i] = s[i];
}

// ------------------------- emit keypoints + scores (fp32) ------------------
__global__ void emit_k(const unsigned long long* __restrict__ keys,
                       float* __restrict__ kp, float* __restrict__ sc)
{
    int tid = blockIdx.x * 256 + threadIdx.x;      // 4 * 4096
    int b = tid >> 12;
    int r = tid & 4095;
    unsigned long long key = keys[(size_t)b * 16384 + r];
    unsigned idx = (unsigned)(key & 0xFFFFFFFFu);
    unsigned hi  = (unsigned)(key >> 32);
    unsigned sk  = ~hi;
    unsigned u   = (sk & 0x80000000u) ? (sk ^ 0x80000000u) : ~sk;
    float val = __uint_as_float(u);
    float tx = (float)(idx % 96);
    float ty = (float)(idx / 96);
    kp[(size_t)tid * 2 + 0] = tx;
    kp[(size_t)tid * 2 + 1] = ty;
    sc[tid] = val;
}

// --------------------- descriptor gather + L2 normalize (fp32) -------------
__global__ __launch_bounds__(256) void desc_out_k(const unsigned long long* __restrict__ keys,
                                                  const float* __restrict__ dm,
                                                  float* __restrict__ outd)
{
    int warp = threadIdx.x >> 6, lane = threadIdx.x & 63;
    int kpid = blockIdx.x * 4 + warp;              // 0..16383
    int b = kpid >> 12, r = kpid & 4095;
    unsigned long long key = keys[(size_t)b * 16384 + r];
    int idx = (int)(unsigned)(key & 0xFFFFFFFFu);
    float v = dm[((size_t)b * 64 + lane) * 9216 + idx];
    float ss = v * v;
#pragma unroll
    for (int o = 32; o > 0; o >>= 1) ss += __shfl_xor(ss, o, 64);
    float n = fmaxf(sqrtf(ss), 1e-12f);
    outd[(size_t)kpid * 64 + lane] = v / n;
}

// ---------------------------------------------------------------------------
extern "C" void kernel_launch(void* const* d_in, const int* in_sizes, int n_in,
                              void* d_out, int out_size, void* d_ws, size_t ws_size,
                              hipStream_t stream)
{
    const float* x      = (const float*)d_in[0];
    const float* w1     = (const float*)d_in[1];
    const float* g1     = (const float*)d_in[2];
    const float* b1     = (const float*)d_in[3];
    const float* w2     = (const float*)d_in[4];
    const float* g2     = (const float*)d_in[5];
    const float* b2     = (const float*)d_in[6];
    const float* w3     = (const float*)d_in[7];
    const float* g3     = (const float*)d_in[8];
    const float* b3     = (const float*)d_in[9];
    const float* w4     = (const float*)d_in[10];
    const float* g4     = (const float*)d_in[11];
    const float* b4     = (const float*)d_in[12];
    const float* wf     = (const float*)d_in[13];
    const float* bf     = (const float*)d_in[14];
    const float* det_w1 = (const float*)d_in[15];
    const float* det_b1 = (const float*)d_in[16];
    const float* det_g  = (const float*)d_in[17];
    const float* det_be = (const float*)d_in[18];
    const float* det_w2 = (const float*)d_in[19];
    const float* det_b2 = (const float*)d_in[20];
    const float* ds_w1  = (const float*)d_in[21];
    const float* ds_b1  = (const float*)d_in[22];
    const float* ds_g1  = (const float*)d_in[23];
    const float* ds_be1 = (const float*)d_in[24];
    const float* ds_w2  = (const float*)d_in[25];
    const float* ds_b2  = (const float*)d_in[26];
    const float* ds_g2  = (const float*)d_in[27];
    const float* ds_be2 = (const float*)d_in[28];

    char* ws = (char*)d_ws;
    // ---- misc persistent buffers at base [0, 819,968) ----
    float* scorem = (float*)(ws + 0);                              // [4,9216]
    unsigned long long* keys = (unsigned long long*)(ws + 147456); // [4,16384]
    float* wc  = (float*)(ws + 671744);                            // [64,64,9]
    float* pc  = (float*)(ws + 819200);                            // 768 B
    float* cbc = pc, *gc = pc + 64, *bec = pc + 128;
    const size_t B0 = 819968;

    pack_head_k<<<72, 256, 0, stream>>>(det_w1, det_b1, det_g, det_be,
                                        ds_w1, ds_b1, ds_g1, ds_be1,
                                        wc, cbc, gc, bec);

    float* desc_full;

    if (ws_size >= 59200000ull) {
        // =============== Layout A (peak 59,028,224 B) ======================
        float* c1pb  = (float*)(ws + B0);           // [32,386,386]   (phase 1)
        float* c2p   = (float*)(ws + 20488960);     // [4,64,194,194]
        float* c3p   = (float*)(ws + B0);           // [4,128,98,98]  (phase 2)
        float* c4    = (float*)(ws + 20488960);     // [4,256,96,96]  (phase 3)
        float* featp = (float*)(ws + B0);           // [4,64,98,98]   (phase 4)
        float* dd1   = (float*)(ws + 10654464);     // [4,64,96,96]
        desc_full    = (float*)(ws + 20488960);     // [4,64,96,96]

        zero_k<<<2048, 256, 0, stream>>>((float4*)(ws + B0), 3638016);

        for (int b = 0; b < 4; b++) {
            conv3x3b_k<3, 32, 4, 3, 384, 2, 1, 4, 1, 1, 1><<<96 * 8, 384, 0, stream>>>(
                x + (size_t)b * 3 * 768 * 768, w1, nullptr, g1, b1, c1pb);
            conv3x3p_k<32, 64, 4, 32, 192, 2, 1, 4, 1, 1, 1><<<48 * 16, 192, 0, stream>>>(
                c1pb, w2, nullptr, g2, b2, c2p + (size_t)b * 2408704);
        }
        zero_k<<<2048, 256, 0, stream>>>((float4*)(ws + B0), 1229312);
        conv3x3p_k<64, 128, 4, 32, 96, 2, 2, 4, 1, 1, 1><<<12 * 32 * 4, 192, 0, stream>>>(
            c2p, w3, nullptr, g3, b3, c3p);
        conv3x3p_k<128, 256, 4, 32, 96, 1, 2, 4, 1, 1, 0><<<12 * 64 * 4, 192, 0, stream>>>(
            c3p, w4, nullptr, g4, b4, c4);
        zero_k<<<2048, 256, 0, stream>>>((float4*)(ws + B0), 614656);
        conv1x1p_k<256, 64, 8, 64, 2, 4, 0, 0, 1><<<12 * 8 * 4, 192, 0, stream>>>(
            c4, wf, bf, nullptr, nullptr, featp, 256, 0);
        conv3x3p_k<64, 64, 4, 32, 96, 1, 2, 4, 1, 1, 0><<<12 * 16 * 4, 192, 0, stream>>>(
            featp, wc, cbc, gc, bec, dd1);
        conv1x1p_k<32, 1, 1, 32, 2, 4, 0, 0, 0><<<12 * 1 * 4, 192, 0, stream>>>(
            dd1, det_w2, det_b2, nullptr, nullptr, scorem, 64, 0);
        conv1x1p_k<32, 64, 8, 32, 2, 4, 0, 1, 0><<<12 * 8 * 4, 192, 0, stream>>>(
            dd1, ds_w2, ds_b2, ds_g2, ds_be2, desc_full, 64, 32);
    } else {
        // =============== Layout B (peak 57,443,072 B, proven) ==============
        float* c3    = (float*)(ws + B0);           // [4,128,96,96] unpadded
        float* c1pb  = (float*)(ws + 19694336);     // [32,386,386]
        float* c2pb  = (float*)(ws + 38765824);     // [64,194,194]
        float* c4    = (float*)(ws + 19694336);     // [4,256,96,96]
        float* featp = (float*)(ws + B0);           // [4,64,98,98]
        float* dd1   = (float*)(ws + 10654464);     // [4,64,96,96]
        desc_full    = (float*)(ws + 20091648);     // [4,64,96,96]

        zero_k<<<2048, 256, 0, stream>>>((float4*)(ws + B0), 2973792);

        for (int b = 0; b < 4; b++) {
            conv3x3b_k<3, 32, 4, 3, 384, 2, 1, 4, 1, 1, 1><<<96 * 8, 384, 0, stream>>>(
                x + (size_t)b * 3 * 768 * 768, w1, nullptr, g1, b1, c1pb);
            conv3x3p_k<32, 64, 4, 32, 192, 2, 1, 4, 1, 1, 1><<<48 * 16, 192, 0, stream>>>(
                c1pb, w2, nullptr, g2, b2, c2pb);
            conv3x3p_k<64, 128, 4, 32, 96, 2, 2, 4, 1, 1, 0><<<12 * 32, 192, 0, stream>>>(
                c2pb, w3, nullptr, g3, b3, c3 + (size_t)b * 1179648);
        }
        conv3x3b_k<128, 256, 4, 32, 96, 1, 2, 4, 1, 1, 0><<<12 * 64 * 4, 192, 0, stream>>>(
            c3, w4, nullptr, g4, b4, c4);
        zero_k<<<2048, 256, 0, stream>>>((float4*)(ws + B0), 614656);
        conv1x1p_k<256, 64, 8, 64, 2, 4, 0, 0, 1><<<12 * 8 * 4, 192, 0, stream>>>(
            c4, wf, bf, nullptr, nullptr, featp, 256, 0);
        conv3x3p_k<64, 64, 4, 32, 96, 1, 2, 4, 1, 1, 0><<<12 * 16 * 4, 192, 0, stream>>>(
            featp, wc, cbc, gc, bec, dd1);
        conv1x1p_k<32, 1, 1, 32, 2, 4, 0, 0, 0><<<12 * 1 * 4, 192, 0, stream>>>(
            dd1, det_w2, det_b2, nullptr, nullptr, scorem, 64, 0);
        conv1x1p_k<32, 64, 8, 32, 2, 4, 0, 1, 0><<<12 * 8 * 4, 192, 0, stream>>>(
            dd1, ds_w2, ds_b2, ds_g2, ds_be2, desc_full, 64, 32);
    }

    nms_keys_k<<<256, 256, 0, stream>>>(scorem, keys);
    sort_k<<<4, 1024, 0, stream>>>(keys);

    float* out_kp = (float*)d_out;
    float* out_sc = out_kp + 4 * 4096 * 2;
    float* out_d  = out_sc + 4 * 4096;
    emit_k<<<64, 256, 0, stream>>>(keys, out_kp, out_sc);
    desc_out_k<<<4096, 256, 0, stream>>>(keys, desc_full, out_d);
}

// Round 13
// 1371.748 us; speedup vs baseline: 2.2973x; 1.6162x over previous
//
#include <hip/hip_runtime.h>

// ---------------------------------------------------------------------------
// XFeat detector: fp64-accumulation direct convs (fp32 storage).
// r13 = exact r10 revert (proven best: 1371 us). CPT=4, P=4, CHUNK=32,
// launch_bounds(.,4). r11 (CPT8/P2) hit the LDS pipe; r12 (prefetch) hit
// register pressure — both regressed. Channel-accumulation order identical
// to r7 -> bit-exact scores -> identical ranking.
// Output (fp32): [kp 4*4096*2 | sc 4*4096 | d 4*4096*64]
// Layout A (ws>=59.2MB, peak 59.03MB) / B (proven-safe peak 57,443,072 B).
// ---------------------------------------------------------------------------

#define EPS_BN 1e-5f

// ------------------------------ zero fill ----------------------------------
__global__ void zero_k(float4* __restrict__ p, size_t n)
{
    for (size_t i = (size_t)blockIdx.x * 256 + threadIdx.x; i < n;
         i += (size_t)gridDim.x * 256)
        p[i] = make_float4(0.f, 0.f, 0.f, 0.f);
}

// ---------- 3x3 conv, BOUNDS-CHECKED input (unpadded), fp64 acc ------------
template<int CIN,int COUT,int CPT,int CHUNK,int HOUT,int STRIDE,int TY,int P,
         int RELU,int BN,int PADOUT>
__global__ __launch_bounds__(HOUT*TY, 4)
void conv3x3b_k(const float* __restrict__ in, const float* __restrict__ wgt,
                const float* __restrict__ cbias, const float* __restrict__ gg,
                const float* __restrict__ bb, float* __restrict__ out)
{
    constexpr int HIN = HOUT * STRIDE;
    constexpr int NG  = COUT / CPT;
    constexpr int YB  = HOUT / (TY * P);
    constexpr int BLK = HOUT * TY;
    constexpr int NR  = (P - 1) * STRIDE + 3;
    static_assert(CIN % CHUNK == 0, "chunk");

    __shared__ double wl[CPT * CHUNK * 9];

    int bid = blockIdx.x;
    int yb  = bid % YB;  int r2 = bid / YB;
    int cog = r2 % NG;   int b  = r2 / NG;
    int tid = threadIdx.x;
    int x   = tid % HOUT;
    int ty  = tid / HOUT;
    int yo0 = (yb * TY + ty) * P;
    int cobase = cog * CPT;

    int xoff[3]; bool okx[3];
#pragma unroll
    for (int kx = 0; kx < 3; kx++) {
        int xi = STRIDE * x - 1 + kx;
        okx[kx]  = (xi >= 0) && (xi < HIN);
        xoff[kx] = min(max(xi, 0), HIN - 1);
    }
    int yoff[NR]; bool oky[NR];
#pragma unroll
    for (int r = 0; r < NR; r++) {
        int yi = STRIDE * yo0 - 1 + r;
        oky[r]  = (yi >= 0) && (yi < HIN);
        yoff[r] = min(max(yi, 0), HIN - 1) * HIN;
    }

    double acc[CPT][P];
#pragma unroll
    for (int co = 0; co < CPT; co++)
#pragma unroll
        for (int p = 0; p < P; p++) acc[co][p] = 0.0;

    const float* inb = in + (size_t)b * CIN * HIN * HIN;

    for (int c0 = 0; c0 < CIN; c0 += CHUNK) {
        __syncthreads();
        for (int i = tid; i < CPT * CHUNK * 9; i += BLK) {
            int k  = i % 9;
            int t2 = i / 9;
            int cc = t2 % CHUNK;
            int co = t2 / CHUNK;
            wl[i] = (double)wgt[((size_t)(cobase + co) * CIN + (c0 + cc)) * 9 + k];
        }
        __syncthreads();

        for (int cc = 0; cc < CHUNK; cc++) {
            const float* inp = inb + (size_t)(c0 + cc) * HIN * HIN;
            double v[NR][3];
#pragma unroll
            for (int r = 0; r < NR; r++)
#pragma unroll
                for (int kx = 0; kx < 3; kx++) {
                    float t = inp[yoff[r] + xoff[kx]];
                    v[r][kx] = (oky[r] && okx[kx]) ? (double)t : 0.0;
                }
#pragma unroll
            for (int co = 0; co < CPT; co++) {
                const double* wp = &wl[(co * CHUNK + cc) * 9];
#pragma unroll
                for (int ky = 0; ky < 3; ky++)
#pragma unroll
                    for (int kx = 0; kx < 3; kx++) {
                        double w = wp[ky * 3 + kx];
#pragma unroll
                        for (int p = 0; p < P; p++)
                            acc[co][p] = fma(v[ky + p * STRIDE][kx], w, acc[co][p]);
                    }
            }
        }
    }

    const float SQ = sqrtf(1.0f + EPS_BN);
    constexpr int WOUT = PADOUT ? HOUT + 2 : HOUT;
    size_t plane = (size_t)WOUT * WOUT;
    float* ob = out + ((size_t)b * COUT + cobase) * plane
              + (PADOUT ? ((size_t)(yo0 + 1) * WOUT + x + 1)
                        : ((size_t)yo0 * WOUT + x));
#pragma unroll
    for (int co = 0; co < CPT; co++) {
        float cb = cbias ? cbias[cobase + co] : 0.f;
#pragma unroll
        for (int p = 0; p < P; p++) {
            float a = (float)acc[co][p] + cb;
            float r;
            if (BN) r = gg[cobase + co] * (a / SQ) + bb[cobase + co];
            else    r = a;
            if (RELU) r = fmaxf(r, 0.f);
            ob[(size_t)co * plane + (size_t)p * WOUT] = r;
        }
    }
}

// ---------- 3x3 conv, PADDED input (no bounds), fp64 acc -------------------
template<int CIN,int COUT,int CPT,int CHUNK,int HOUT,int STRIDE,int TY,int P,
         int RELU,int BN,int PADOUT>
__global__ __launch_bounds__(HOUT*TY, 4)
void conv3x3p_k(const float* __restrict__ in, const float* __restrict__ wgt,
                const float* __restrict__ cbias, const float* __restrict__ gg,
                const float* __restrict__ bb, float* __restrict__ out)
{
    constexpr int HIN = HOUT * STRIDE;
    constexpr int PIN = HIN + 2;
    constexpr int NG  = COUT / CPT;
    constexpr int YB  = HOUT / (TY * P);
    constexpr int BLK = HOUT * TY;
    constexpr int NR  = (P - 1) * STRIDE + 3;
    constexpr size_t PIN2 = (size_t)PIN * PIN;
    static_assert(CIN % CHUNK == 0, "chunk");

    __shared__ double wl[CPT * CHUNK * 9];

    int bid = blockIdx.x;
    int yb  = bid % YB;  int r2 = bid / YB;
    int cog = r2 % NG;   int b  = r2 / NG;
    int tid = threadIdx.x;
    int x   = tid % HOUT;
    int ty  = tid / HOUT;
    int yo0 = (yb * TY + ty) * P;
    int cobase = cog * CPT;

    double acc[CPT][P];
#pragma unroll
    for (int co = 0; co < CPT; co++)
#pragma unroll
        for (int p = 0; p < P; p++) acc[co][p] = 0.0;

    const float* inb = in + (size_t)b * CIN * PIN2
                     + (size_t)(STRIDE * yo0) * PIN + STRIDE * x;

    for (int c0 = 0; c0 < CIN; c0 += CHUNK) {
        __syncthreads();
        for (int i = tid; i < CPT * CHUNK * 9; i += BLK) {
            int k  = i % 9;
            int t2 = i / 9;
            int cc = t2 % CHUNK;
            int co = t2 / CHUNK;
            wl[i] = (double)wgt[((size_t)(cobase + co) * CIN + (c0 + cc)) * 9 + k];
        }
        __syncthreads();

        const float* ip = inb + (size_t)c0 * PIN2;
        for (int cc = 0; cc < CHUNK; cc++) {
            double v[NR][3];
#pragma unroll
            for (int r = 0; r < NR; r++)
#pragma unroll
                for (int kx = 0; kx < 3; kx++)
                    v[r][kx] = (double)ip[(size_t)r * PIN + kx];
#pragma unroll
            for (int co = 0; co < CPT; co++) {
                const double* wp = &wl[(co * CHUNK + cc) * 9];
#pragma unroll
                for (int ky = 0; ky < 3; ky++)
#pragma unroll
                    for (int kx = 0; kx < 3; kx++) {
                        double w = wp[ky * 3 + kx];
#pragma unroll
                        for (int p = 0; p < P; p++)
                            acc[co][p] = fma(v[ky + p * STRIDE][kx], w, acc[co][p]);
                    }
            }
            ip += PIN2;
        }
    }

    const float SQ = sqrtf(1.0f + EPS_BN);
    constexpr int WOUT = PADOUT ? HOUT + 2 : HOUT;
    size_t plane = (size_t)WOUT * WOUT;
    float* ob = out + ((size_t)b * COUT + cobase) * plane
              + (PADOUT ? ((size_t)(yo0 + 1) * WOUT + x + 1)
                        : ((size_t)yo0 * WOUT + x));
#pragma unroll
    for (int co = 0; co < CPT; co++) {
        float cb = cbias ? cbias[cobase + co] : 0.f;
#pragma unroll
        for (int p = 0; p < P; p++) {
            float a = (float)acc[co][p] + cb;
            float r;
            if (BN) r = gg[cobase + co] * (a / SQ) + bb[cobase + co];
            else    r = a;
            if (RELU) r = fmaxf(r, 0.f);
            ob[(size_t)co * plane + (size_t)p * WOUT] = r;
        }
    }
}

// ---------------- 1x1 conv (fp64 acc, fp64 LDS weights) --------------------
template<int CIN,int COUT,int CPT,int CHUNK,int TY,int P,int RELU,int BN,int PADOUT>
__global__ __launch_bounds__(96*TY, 4)
void conv1x1p_k(const float* __restrict__ in, const float* __restrict__ wgt,
                const float* __restrict__ cbias, const float* __restrict__ gg,
                const float* __restrict__ bb, float* __restrict__ out,
                int cin_tot, int cin_off)
{
    constexpr int HOUT = 96;
    constexpr int HW   = 96 * 96;
    constexpr int NG   = COUT / CPT;
    constexpr int YB   = HOUT / (TY * P);
    constexpr int BLK  = 96 * TY;

    __shared__ double wl[CPT * CHUNK];

    int bid = blockIdx.x;
    int yb  = bid % YB;  int r2 = bid / YB;
    int cog = r2 % NG;   int b  = r2 / NG;
    int tid = threadIdx.x;
    int x   = tid % HOUT;
    int ty  = tid / HOUT;
    int yo0 = (yb * TY + ty) * P;
    int cobase = cog * CPT;

    double acc[CPT][P];
#pragma unroll
    for (int co = 0; co < CPT; co++)
#pragma unroll
        for (int p = 0; p < P; p++) acc[co][p] = 0.0;

    const float* inb = in + ((size_t)b * cin_tot + cin_off) * HW + (size_t)yo0 * HOUT + x;

    for (int c0 = 0; c0 < CIN; c0 += CHUNK) {
        __syncthreads();
        for (int i = tid; i < CPT * CHUNK; i += BLK) {
            int cc = i % CHUNK;
            int co = i / CHUNK;
            wl[i] = (double)wgt[(size_t)(cobase + co) * CIN + (c0 + cc)];
        }
        __syncthreads();
        for (int cc = 0; cc < CHUNK; cc++) {
            const float* inp = inb + (size_t)(c0 + cc) * HW;
            double v[P];
#pragma unroll
            for (int p = 0; p < P; p++) v[p] = (double)inp[p * HOUT];
#pragma unroll
            for (int co = 0; co < CPT; co++) {
                double w = wl[co * CHUNK + cc];
#pragma unroll
                for (int p = 0; p < P; p++) acc[co][p] = fma(v[p], w, acc[co][p]);
            }
        }
    }

    const float SQ = sqrtf(1.0f + EPS_BN);
    constexpr int WOUT = PADOUT ? 98 : 96;
    size_t plane = (size_t)WOUT * WOUT;
    float* ob = out + ((size_t)b * COUT + cobase) * plane
              + (PADOUT ? ((size_t)(yo0 + 1) * WOUT + x + 1)
                        : ((size_t)yo0 * WOUT + x));
#pragma unroll
    for (int co = 0; co < CPT; co++) {
        float cb = cbias ? cbias[cobase + co] : 0.f;
#pragma unroll
        for (int p = 0; p < P; p++) {
            float a = (float)acc[co][p] + cb;
            float r;
            if (BN) r = gg[cobase + co] * (a / SQ) + bb[cobase + co];
            else    r = a;
            if (RELU) r = fmaxf(r, 0.f);
            ob[(size_t)co * plane + (size_t)p * WOUT] = r;
        }
    }
}

// --------------- pack det/desc head-1 weights into one 64-ch conv ----------
__global__ void pack_head_k(const float* __restrict__ dw, const float* __restrict__ db,
                            const float* __restrict__ dg, const float* __restrict__ dbe,
                            const float* __restrict__ sw, const float* __restrict__ sb,
                            const float* __restrict__ sg, const float* __restrict__ sbe,
                            float* __restrict__ wc, float* __restrict__ cbc,
                            float* __restrict__ gc, float* __restrict__ bec)
{
    int i = blockIdx.x * 256 + threadIdx.x;
    const int WN = 32 * 64 * 9;
    if (i < WN) { wc[i] = dw[i]; wc[WN + i] = sw[i]; }
    if (i < 32) {
        cbc[i] = db[i]; cbc[32 + i] = sb[i];
        gc[i]  = dg[i]; gc[32 + i]  = sg[i];
        bec[i] = dbe[i]; bec[32 + i] = sbe[i];
    }
}

// ------------------------- NMS + sortable key build ------------------------
__global__ void nms_keys_k(const float* __restrict__ score, unsigned long long* __restrict__ keys)
{
    int tid = blockIdx.x * 256 + threadIdx.x;      // 4 * 16384
    int b = tid >> 14;
    int i = tid & 16383;
    unsigned long long key = ~0ULL;                // padding sorts last
    if (i < 9216) {
        int y = i / 96, x = i % 96;
        const float* sb = score + (size_t)b * 9216;
        float s = sb[i];
        float m = -INFINITY;
#pragma unroll
        for (int dy = -2; dy <= 1; dy++) {
            int yy = y + dy;
            if (yy < 0 || yy >= 96) continue;
#pragma unroll
            for (int dx = -2; dx <= 1; dx++) {
                int xx = x + dx;
                if (xx < 0 || xx >= 96) continue;
                m = fmaxf(m, sb[yy * 96 + xx]);
            }
        }
        float nv = (s == m) ? s : 0.0f;
        if (nv == 0.0f) nv = 0.0f;                 // canonicalize -0.0 -> +0.0
        unsigned u = __float_as_uint(nv);
        unsigned sk = (u & 0x80000000u) ? ~u : (u | 0x80000000u);
        key = ((unsigned long long)(~sk) << 32) | (unsigned)i;
    }
    keys[(size_t)b * 16384 + i] = key;
}

// ------------------------- bitonic sort (per batch) ------------------------
__global__ __launch_bounds__(1024) void sort_k(unsigned long long* __restrict__ keys)
{
    __shared__ unsigned long long s[16384];
    unsigned long long* kb = keys + (size_t)blockIdx.x * 16384;
    for (int i = threadIdx.x; i < 16384; i += 1024) s[i] = kb[i];
    __syncthreads();
    for (int k = 2; k <= 16384; k <<= 1) {
        for (int j = k >> 1; j > 0; j >>= 1) {
            for (int i = threadIdx.x; i < 16384; i += 1024) {
                int ixj = i ^ j;
                if (ixj > i) {
                    unsigned long long a = s[i], c = s[ixj];
                    bool up = ((i & k) == 0);
                    if ((a > c) == up) { s[i] = c; s[ixj] = a; }
                }
            }
            __syncthreads();
        }
    }
    for (int i = threadIdx.x; i < 16384; i += 1024) kb[i] = s[i];
}

// ------------------------- emit keypoints + scores (fp32) ------------------
__global__ void emit_k(const unsigned long long* __restrict__ keys,
                       float* __restrict__ kp, float* __restrict__ sc)
{
    int tid = blockIdx.x * 256 + threadIdx.x;      // 4 * 4096
    int b = tid >> 12;
    int r = tid & 4095;
    unsigned long long key = keys[(size_t)b * 16384 + r];
    unsigned idx = (unsigned)(key & 0xFFFFFFFFu);
    unsigned hi  = (unsigned)(key >> 32);
    unsigned sk  = ~hi;
    unsigned u   = (sk & 0x80000000u) ? (sk ^ 0x80000000u) : ~sk;
    float val = __uint_as_float(u);
    float tx = (float)(idx % 96);
    float ty = (float)(idx / 96);
    kp[(size_t)tid * 2 + 0] = tx;
    kp[(size_t)tid * 2 + 1] = ty;
    sc[tid] = val;
}

// --------------------- descriptor gather + L2 normalize (fp32) -------------
__global__ __launch_bounds__(256) void desc_out_k(const unsigned long long* __restrict__ keys,
                                                  const float* __restrict__ dm,
                                                  float* __restrict__ outd)
{
    int warp = threadIdx.x >> 6, lane = threadIdx.x & 63;
    int kpid = blockIdx.x * 4 + warp;              // 0..16383
    int b = kpid >> 12, r = kpid & 4095;
    unsigned long long key = keys[(size_t)b * 16384 + r];
    int idx = (int)(unsigned)(key & 0xFFFFFFFFu);
    float v = dm[((size_t)b * 64 + lane) * 9216 + idx];
    float ss = v * v;
#pragma unroll
    for (int o = 32; o > 0; o >>= 1) ss += __shfl_xor(ss, o, 64);
    float n = fmaxf(sqrtf(ss), 1e-12f);
    outd[(size_t)kpid * 64 + lane] = v / n;
}

// ---------------------------------------------------------------------------
extern "C" void kernel_launch(void* const* d_in, const int* in_sizes, int n_in,
                              void* d_out, int out_size, void* d_ws, size_t ws_size,
                              hipStream_t stream)
{
    const float* x      = (const float*)d_in[0];
    const float* w1     = (const float*)d_in[1];
    const float* g1     = (const float*)d_in[2];
    const float* b1     = (const float*)d_in[3];
    const float* w2     = (const float*)d_in[4];
    const float* g2     = (const float*)d_in[5];
    const float* b2     = (const float*)d_in[6];
    const float* w3     = (const float*)d_in[7];
    const float* g3     = (const float*)d_in[8];
    const float* b3     = (const float*)d_in[9];
    const float* w4     = (const float*)d_in[10];
    const float* g4     = (const float*)d_in[11];
    const float* b4     = (const float*)d_in[12];
    const float* wf     = (const float*)d_in[13];
    const float* bf     = (const float*)d_in[14];
    const float* det_w1 = (const float*)d_in[15];
    const float* det_b1 = (const float*)d_in[16];
    const float* det_g  = (const float*)d_in[17];
    const float* det_be = (const float*)d_in[18];
    const float* det_w2 = (const float*)d_in[19];
    const float* det_b2 = (const float*)d_in[20];
    const float* ds_w1  = (const float*)d_in[21];
    const float* ds_b1  = (const float*)d_in[22];
    const float* ds_g1  = (const float*)d_in[23];
    const float* ds_be1 = (const float*)d_in[24];
    const float* ds_w2  = (const float*)d_in[25];
    const float* ds_b2  = (const float*)d_in[26];
    const float* ds_g2  = (const float*)d_in[27];
    const float* ds_be2 = (const float*)d_in[28];

    char* ws = (char*)d_ws;
    // ---- misc persistent buffers at base [0, 819,968) ----
    float* scorem = (float*)(ws + 0);                              // [4,9216]
    unsigned long long* keys = (unsigned long long*)(ws + 147456); // [4,16384]
    float* wc  = (float*)(ws + 671744);                            // [64,64,9]
    float* pc  = (float*)(ws + 819200);                            // 768 B
    float* cbc = pc, *gc = pc + 64, *bec = pc + 128;
    const size_t B0 = 819968;

    pack_head_k<<<72, 256, 0, stream>>>(det_w1, det_b1, det_g, det_be,
                                        ds_w1, ds_b1, ds_g1, ds_be1,
                                        wc, cbc, gc, bec);

    float* desc_full;

    if (ws_size >= 59200000ull) {
        // =============== Layout A (peak 59,028,224 B) ======================
        float* c1pb  = (float*)(ws + B0);           // [32,386,386]   (phase 1)
        float* c2p   = (float*)(ws + 20488960);     // [4,64,194,194]
        float* c3p   = (float*)(ws + B0);           // [4,128,98,98]  (phase 2)
        float* c4    = (float*)(ws + 20488960);     // [4,256,96,96]  (phase 3)
        float* featp = (float*)(ws + B0);           // [4,64,98,98]   (phase 4)
        float* dd1   = (float*)(ws + 10654464);     // [4,64,96,96]
        desc_full    = (float*)(ws + 20488960);     // [4,64,96,96]

        zero_k<<<2048, 256, 0, stream>>>((float4*)(ws + B0), 3638016);

        for (int b = 0; b < 4; b++) {
            conv3x3b_k<3, 32, 4, 3, 384, 2, 1, 4, 1, 1, 1><<<96 * 8, 384, 0, stream>>>(
                x + (size_t)b * 3 * 768 * 768, w1, nullptr, g1, b1, c1pb);
            conv3x3p_k<32, 64, 4, 32, 192, 2, 1, 4, 1, 1, 1><<<48 * 16, 192, 0, stream>>>(
                c1pb, w2, nullptr, g2, b2, c2p + (size_t)b * 2408704);
        }
        zero_k<<<2048, 256, 0, stream>>>((float4*)(ws + B0), 1229312);
        conv3x3p_k<64, 128, 4, 32, 96, 2, 2, 4, 1, 1, 1><<<12 * 32 * 4, 192, 0, stream>>>(
            c2p, w3, nullptr, g3, b3, c3p);
        conv3x3p_k<128, 256, 4, 32, 96, 1, 2, 4, 1, 1, 0><<<12 * 64 * 4, 192, 0, stream>>>(
            c3p, w4, nullptr, g4, b4, c4);
        zero_k<<<2048, 256, 0, stream>>>((float4*)(ws + B0), 614656);
        conv1x1p_k<256, 64, 8, 64, 2, 4, 0, 0, 1><<<12 * 8 * 4, 192, 0, stream>>>(
            c4, wf, bf, nullptr, nullptr, featp, 256, 0);
        conv3x3p_k<64, 64, 4, 32, 96, 1, 2, 4, 1, 1, 0><<<12 * 16 * 4, 192, 0, stream>>>(
            featp, wc, cbc, gc, bec, dd1);
        conv1x1p_k<32, 1, 1, 32, 2, 4, 0, 0, 0><<<12 * 1 * 4, 192, 0, stream>>>(
            dd1, det_w2, det_b2, nullptr, nullptr, scorem, 64, 0);
        conv1x1p_k<32, 64, 8, 32, 2, 4, 0, 1, 0><<<12 * 8 * 4, 192, 0, stream>>>(
            dd1, ds_w2, ds_b2, ds_g2, ds_be2, desc_full, 64, 32);
    } else {
        // =============== Layout B (peak 57,443,072 B, proven) ==============
        float* c3    = (float*)(ws + B0);           // [4,128,96,96] unpadded
        float* c1pb  = (float*)(ws + 19694336);     // [32,386,386]
        float* c2pb  = (float*)(ws + 38765824);     // [64,194,194]
        float* c4    = (float*)(ws + 19694336);     // [4,256,96,96]
        float* featp = (float*)(ws + B0);           // [4,64,98,98]
        float* dd1   = (float*)(ws + 10654464);     // [4,64,96,96]
        desc_full    = (float*)(ws + 20091648);     // [4,64,96,96]

        zero_k<<<2048, 256, 0, stream>>>((float4*)(ws + B0), 2973792);

        for (int b = 0; b < 4; b++) {
            conv3x3b_k<3, 32, 4, 3, 384, 2, 1, 4, 1, 1, 1><<<96 * 8, 384, 0, stream>>>(
                x + (size_t)b * 3 * 768 * 768, w1, nullptr, g1, b1, c1pb);
            conv3x3p_k<32, 64, 4, 32, 192, 2, 1, 4, 1, 1, 1><<<48 * 16, 192, 0, stream>>>(
                c1pb, w2, nullptr, g2, b2, c2pb);
            conv3x3p_k<64, 128, 4, 32, 96, 2, 2, 4, 1, 1, 0><<<12 * 32, 192, 0, stream>>>(
                c2pb, w3, nullptr, g3, b3, c3 + (size_t)b * 1179648);
        }
        conv3x3b_k<128, 256, 4, 32, 96, 1, 2, 4, 1, 1, 0><<<12 * 64 * 4, 192, 0, stream>>>(
            c3, w4, nullptr, g4, b4, c4);
        zero_k<<<2048, 256, 0, stream>>>((float4*)(ws + B0), 614656);
        conv1x1p_k<256, 64, 8, 64, 2, 4, 0, 0, 1><<<12 * 8 * 4, 192, 0, stream>>>(
            c4, wf, bf, nullptr, nullptr, featp, 256, 0);
        conv3x3p_k<64, 64, 4, 32, 96, 1, 2, 4, 1, 1, 0><<<12 * 16 * 4, 192, 0, stream>>>(
            featp, wc, cbc, gc, bec, dd1);
        conv1x1p_k<32, 1, 1, 32, 2, 4, 0, 0, 0><<<12 * 1 * 4, 192, 0, stream>>>(
            dd1, det_w2, det_b2, nullptr, nullptr, scorem, 64, 0);
        conv1x1p_k<32, 64, 8, 32, 2, 4, 0, 1, 0><<<12 * 8 * 4, 192, 0, stream>>>(
            dd1, ds_w2, ds_b2, ds_g2, ds_be2, desc_full, 64, 32);
    }

    nms_keys_k<<<256, 256, 0, stream>>>(scorem, keys);
    sort_k<<<4, 1024, 0, stream>>>(keys);

    float* out_kp = (float*)d_out;
    float* out_sc = out_kp + 4 * 4096 * 2;
    float* out_d  = out_sc + 4 * 4096;
    emit_k<<<64, 256, 0, stream>>>(keys, out_kp, out_sc);
    desc_out_k<<<4096, 256, 0, stream>>>(keys, desc_full, out_d);
}

// Round 14
// 1354.776 us; speedup vs baseline: 2.3261x; 1.0125x over previous
//
#include <hip/hip_runtime.h>

// ---------------------------------------------------------------------------
// XFeat detector: HYBRID accumulation direct convs.
// 3x3 convs: per-channel 9-tap dot in fp32 (error ~2e-7), summed across
// channels in fp64 (exact) -> score noise ~1.5e-7 rel, ~13x better than the
// failed all-fp32 r6 (~2e-6), ~1.7x less VALU than all-fp64 r13.
// 1x1 convs remain pure fp64. Channel order unchanged.
// Output (fp32): [kp 4*4096*2 | sc 4*4096 | d 4*4096*64]
// Layout A (ws>=59.2MB, peak 59.03MB) / B (peak 57,443,072 B).
// ---------------------------------------------------------------------------

#define EPS_BN 1e-5f

// ------------------------------ zero fill ----------------------------------
__global__ void zero_k(float4* __restrict__ p, size_t n)
{
    for (size_t i = (size_t)blockIdx.x * 256 + threadIdx.x; i < n;
         i += (size_t)gridDim.x * 256)
        p[i] = make_float4(0.f, 0.f, 0.f, 0.f);
}

// ---------- 3x3 conv, BOUNDS-CHECKED input (unpadded), hybrid acc ----------
template<int CIN,int COUT,int CPT,int CHUNK,int HOUT,int STRIDE,int TY,int P,
         int RELU,int BN,int PADOUT>
__global__ __launch_bounds__(HOUT*TY, 4)
void conv3x3b_k(const float* __restrict__ in, const float* __restrict__ wgt,
                const float* __restrict__ cbias, const float* __restrict__ gg,
                const float* __restrict__ bb, float* __restrict__ out)
{
    constexpr int HIN = HOUT * STRIDE;
    constexpr int NG  = COUT / CPT;
    constexpr int YB  = HOUT / (TY * P);
    constexpr int BLK = HOUT * TY;
    constexpr int NR  = (P - 1) * STRIDE + 3;
    static_assert(CIN % CHUNK == 0, "chunk");

    __shared__ float wl[CPT * CHUNK * 9];

    int bid = blockIdx.x;
    int yb  = bid % YB;  int r2 = bid / YB;
    int cog = r2 % NG;   int b  = r2 / NG;
    int tid = threadIdx.x;
    int x   = tid % HOUT;
    int ty  = tid / HOUT;
    int yo0 = (yb * TY + ty) * P;
    int cobase = cog * CPT;

    int xoff[3]; bool okx[3];
#pragma unroll
    for (int kx = 0; kx < 3; kx++) {
        int xi = STRIDE * x - 1 + kx;
        okx[kx]  = (xi >= 0) && (xi < HIN);
        xoff[kx] = min(max(xi, 0), HIN - 1);
    }
    int yoff[NR]; bool oky[NR];
#pragma unroll
    for (int r = 0; r < NR; r++) {
        int yi = STRIDE * yo0 - 1 + r;
        oky[r]  = (yi >= 0) && (yi < HIN);
        yoff[r] = min(max(yi, 0), HIN - 1) * HIN;
    }

    double acc[CPT][P];
#pragma unroll
    for (int co = 0; co < CPT; co++)
#pragma unroll
        for (int p = 0; p < P; p++) acc[co][p] = 0.0;

    const float* inb = in + (size_t)b * CIN * HIN * HIN;

    for (int c0 = 0; c0 < CIN; c0 += CHUNK) {
        __syncthreads();
        for (int i = tid; i < CPT * CHUNK * 9; i += BLK) {
            int k  = i % 9;
            int t2 = i / 9;
            int cc = t2 % CHUNK;
            int co = t2 / CHUNK;
            wl[i] = wgt[((size_t)(cobase + co) * CIN + (c0 + cc)) * 9 + k];
        }
        __syncthreads();

        for (int cc = 0; cc < CHUNK; cc++) {
            const float* inp = inb + (size_t)(c0 + cc) * HIN * HIN;
            float v[NR][3];
#pragma unroll
            for (int r = 0; r < NR; r++)
#pragma unroll
                for (int kx = 0; kx < 3; kx++) {
                    float t = inp[yoff[r] + xoff[kx]];
                    v[r][kx] = (oky[r] && okx[kx]) ? t : 0.0f;
                }
#pragma unroll
            for (int co = 0; co < CPT; co++) {
                const float* wp = &wl[(co * CHUNK + cc) * 9];
                float s[P];
#pragma unroll
                for (int p = 0; p < P; p++) s[p] = 0.0f;
#pragma unroll
                for (int ky = 0; ky < 3; ky++)
#pragma unroll
                    for (int kx = 0; kx < 3; kx++) {
                        float w = wp[ky * 3 + kx];
#pragma unroll
                        for (int p = 0; p < P; p++)
                            s[p] = fmaf(v[ky + p * STRIDE][kx], w, s[p]);
                    }
#pragma unroll
                for (int p = 0; p < P; p++) acc[co][p] += (double)s[p];
            }
        }
    }

    const float SQ = sqrtf(1.0f + EPS_BN);
    constexpr int WOUT = PADOUT ? HOUT + 2 : HOUT;
    size_t plane = (size_t)WOUT * WOUT;
    float* ob = out + ((size_t)b * COUT + cobase) * plane
              + (PADOUT ? ((size_t)(yo0 + 1) * WOUT + x + 1)
                        : ((size_t)yo0 * WOUT + x));
#pragma unroll
    for (int co = 0; co < CPT; co++) {
        float cb = cbias ? cbias[cobase + co] : 0.f;
#pragma unroll
        for (int p = 0; p < P; p++) {
            float a = (float)acc[co][p] + cb;
            float r;
            if (BN) r = gg[cobase + co] * (a / SQ) + bb[cobase + co];
            else    r = a;
            if (RELU) r = fmaxf(r, 0.f);
            ob[(size_t)co * plane + (size_t)p * WOUT] = r;
        }
    }
}

// ---------- 3x3 conv, PADDED input (no bounds), hybrid acc -----------------
template<int CIN,int COUT,int CPT,int CHUNK,int HOUT,int STRIDE,int TY,int P,
         int RELU,int BN,int PADOUT>
__global__ __launch_bounds__(HOUT*TY, 4)
void conv3x3p_k(const float* __restrict__ in, const float* __restrict__ wgt,
                const float* __restrict__ cbias, const float* __restrict__ gg,
                const float* __restrict__ bb, float* __restrict__ out)
{
    constexpr int HIN = HOUT * STRIDE;
    constexpr int PIN = HIN + 2;
    constexpr int NG  = COUT / CPT;
    constexpr int YB  = HOUT / (TY * P);
    constexpr int BLK = HOUT * TY;
    constexpr int NR  = (P - 1) * STRIDE + 3;
    constexpr size_t PIN2 = (size_t)PIN * PIN;
    static_assert(CIN % CHUNK == 0, "chunk");

    __shared__ float wl[CPT * CHUNK * 9];

    int bid = blockIdx.x;
    int yb  = bid % YB;  int r2 = bid / YB;
    int cog = r2 % NG;   int b  = r2 / NG;
    int tid = threadIdx.x;
    int x   = tid % HOUT;
    int ty  = tid / HOUT;
    int yo0 = (yb * TY + ty) * P;
    int cobase = cog * CPT;

    double acc[CPT][P];
#pragma unroll
    for (int co = 0; co < CPT; co++)
#pragma unroll
        for (int p = 0; p < P; p++) acc[co][p] = 0.0;

    const float* inb = in + (size_t)b * CIN * PIN2
                     + (size_t)(STRIDE * yo0) * PIN + STRIDE * x;

    for (int c0 = 0; c0 < CIN; c0 += CHUNK) {
        __syncthreads();
        for (int i = tid; i < CPT * CHUNK * 9; i += BLK) {
            int k  = i % 9;
            int t2 = i / 9;
            int cc = t2 % CHUNK;
            int co = t2 / CHUNK;
            wl[i] = wgt[((size_t)(cobase + co) * CIN + (c0 + cc)) * 9 + k];
        }
        __syncthreads();

        const float* ip = inb + (size_t)c0 * PIN2;
        for (int cc = 0; cc < CHUNK; cc++) {
            float v[NR][3];
#pragma unroll
            for (int r = 0; r < NR; r++)
#pragma unroll
                for (int kx = 0; kx < 3; kx++)
                    v[r][kx] = ip[(size_t)r * PIN + kx];
#pragma unroll
            for (int co = 0; co < CPT; co++) {
                const float* wp = &wl[(co * CHUNK + cc) * 9];
                float s[P];
#pragma unroll
                for (int p = 0; p < P; p++) s[p] = 0.0f;
#pragma unroll
                for (int ky = 0; ky < 3; ky++)
#pragma unroll
                    for (int kx = 0; kx < 3; kx++) {
                        float w = wp[ky * 3 + kx];
#pragma unroll
                        for (int p = 0; p < P; p++)
                            s[p] = fmaf(v[ky + p * STRIDE][kx], w, s[p]);
                    }
#pragma unroll
                for (int p = 0; p < P; p++) acc[co][p] += (double)s[p];
            }
            ip += PIN2;
        }
    }

    const float SQ = sqrtf(1.0f + EPS_BN);
    constexpr int WOUT = PADOUT ? HOUT + 2 : HOUT;
    size_t plane = (size_t)WOUT * WOUT;
    float* ob = out + ((size_t)b * COUT + cobase) * plane
              + (PADOUT ? ((size_t)(yo0 + 1) * WOUT + x + 1)
                        : ((size_t)yo0 * WOUT + x));
#pragma unroll
    for (int co = 0; co < CPT; co++) {
        float cb = cbias ? cbias[cobase + co] : 0.f;
#pragma unroll
        for (int p = 0; p < P; p++) {
            float a = (float)acc[co][p] + cb;
            float r;
            if (BN) r = gg[cobase + co] * (a / SQ) + bb[cobase + co];
            else    r = a;
            if (RELU) r = fmaxf(r, 0.f);
            ob[(size_t)co * plane + (size_t)p * WOUT] = r;
        }
    }
}

// ---------------- 1x1 conv (pure fp64 acc, fp64 LDS weights) ---------------
template<int CIN,int COUT,int CPT,int CHUNK,int TY,int P,int RELU,int BN,int PADOUT>
__global__ __launch_bounds__(96*TY, 4)
void conv1x1p_k(const float* __restrict__ in, const float* __restrict__ wgt,
                const float* __restrict__ cbias, const float* __restrict__ gg,
                const float* __restrict__ bb, float* __restrict__ out,
                int cin_tot, int cin_off)
{
    constexpr int HOUT = 96;
    constexpr int HW   = 96 * 96;
    constexpr int NG   = COUT / CPT;
    constexpr int YB   = HOUT / (TY * P);
    constexpr int BLK  = 96 * TY;

    __shared__ double wl[CPT * CHUNK];

    int bid = blockIdx.x;
    int yb  = bid % YB;  int r2 = bid / YB;
    int cog = r2 % NG;   int b  = r2 / NG;
    int tid = threadIdx.x;
    int x   = tid % HOUT;
    int ty  = tid / HOUT;
    int yo0 = (yb * TY + ty) * P;
    int cobase = cog * CPT;

    double acc[CPT][P];
#pragma unroll
    for (int co = 0; co < CPT; co++)
#pragma unroll
        for (int p = 0; p < P; p++) acc[co][p] = 0.0;

    const float* inb = in + ((size_t)b * cin_tot + cin_off) * HW + (size_t)yo0 * HOUT + x;

    for (int c0 = 0; c0 < CIN; c0 += CHUNK) {
        __syncthreads();
        for (int i = tid; i < CPT * CHUNK; i += BLK) {
            int cc = i % CHUNK;
            int co = i / CHUNK;
            wl[i] = (double)wgt[(size_t)(cobase + co) * CIN + (c0 + cc)];
        }
        __syncthreads();
        for (int cc = 0; cc < CHUNK; cc++) {
            const float* inp = inb + (size_t)(c0 + cc) * HW;
            double v[P];
#pragma unroll
            for (int p = 0; p < P; p++) v[p] = (double)inp[p * HOUT];
#pragma unroll
            for (int co = 0; co < CPT; co++) {
                double w = wl[co * CHUNK + cc];
#pragma unroll
                for (int p = 0; p < P; p++) acc[co][p] = fma(v[p], w, acc[co][p]);
            }
        }
    }

    const float SQ = sqrtf(1.0f + EPS_BN);
    constexpr int WOUT = PADOUT ? 98 : 96;
    size_t plane = (size_t)WOUT * WOUT;
    float* ob = out + ((size_t)b * COUT + cobase) * plane
              + (PADOUT ? ((size_t)(yo0 + 1) * WOUT + x + 1)
                        : ((size_t)yo0 * WOUT + x));
#pragma unroll
    for (int co = 0; co < CPT; co++) {
        float cb = cbias ? cbias[cobase + co] : 0.f;
#pragma unroll
        for (int p = 0; p < P; p++) {
            float a = (float)acc[co][p] + cb;
            float r;
            if (BN) r = gg[cobase + co] * (a / SQ) + bb[cobase + co];
            else    r = a;
            if (RELU) r = fmaxf(r, 0.f);
            ob[(size_t)co * plane + (size_t)p * WOUT] = r;
        }
    }
}

// --------------- pack det/desc head-1 weights into one 64-ch conv ----------
__global__ void pack_head_k(const float* __restrict__ dw, const float* __restrict__ db,
                            const float* __restrict__ dg, const float* __restrict__ dbe,
                            const float* __restrict__ sw, const float* __restrict__ sb,
                            const float* __restrict__ sg, const float* __restrict__ sbe,
                            float* __restrict__ wc, float* __restrict__ cbc,
                            float* __restrict__ gc, float* __restrict__ bec)
{
    int i = blockIdx.x * 256 + threadIdx.x;
    const int WN = 32 * 64 * 9;
    if (i < WN) { wc[i] = dw[i]; wc[WN + i] = sw[i]; }
    if (i < 32) {
        cbc[i] = db[i]; cbc[32 + i] = sb[i];
        gc[i]  = dg[i]; gc[32 + i]  = sg[i];
        bec[i] = dbe[i]; bec[32 + i] = sbe[i];
    }
}

// ------------------------- NMS + sortable key build ------------------------
__global__ void nms_keys_k(const float* __restrict__ score, unsigned long long* __restrict__ keys)
{
    int tid = blockIdx.x * 256 + threadIdx.x;      // 4 * 16384
    int b = tid >> 14;
    int i = tid & 16383;
    unsigned long long key = ~0ULL;                // padding sorts last
    if (i < 9216) {
        int y = i / 96, x = i % 96;
        const float* sb = score + (size_t)b * 9216;
        float s = sb[i];
        float m = -INFINITY;
#pragma unroll
        for (int dy = -2; dy <= 1; dy++) {
            int yy = y + dy;
            if (yy < 0 || yy >= 96) continue;
#pragma unroll
            for (int dx = -2; dx <= 1; dx++) {
                int xx = x + dx;
                if (xx < 0 || xx >= 96) continue;
                m = fmaxf(m, sb[yy * 96 + xx]);
            }
        }
        float nv = (s == m) ? s : 0.0f;
        if (nv == 0.0f) nv = 0.0f;                 // canonicalize -0.0 -> +0.0
        unsigned u = __float_as_uint(nv);
        unsigned sk = (u & 0x80000000u) ? ~u : (u | 0x80000000u);
        key = ((unsigned long long)(~sk) << 32) | (unsigned)i;
    }
    keys[(size_t)b * 16384 + i] = key;
}

// ------------------------- bitonic sort (per batch) ------------------------
__global__ __launch_bounds__(1024) void sort_k(unsigned long long* __restrict__ keys)
{
    __shared__ unsigned long long s[16384];
    unsigned long long* kb = keys + (size_t)blockIdx.x * 16384;
    for (int i = threadIdx.x; i < 16384; i += 1024) s[i] = kb[i];
    __syncthreads();
    for (int k = 2; k <= 16384; k <<= 1) {
        for (int j = k >> 1; j > 0; j >>= 1) {
            for (int i = threadIdx.x; i < 16384; i += 1024) {
                int ixj = i ^ j;
                if (ixj > i) {
                    unsigned long long a = s[i], c = s[ixj];
                    bool up = ((i & k) == 0);
                    if ((a > c) == up) { s[i] = c; s[ixj] = a; }
                }
            }
            __syncthreads();
        }
    }
    for (int i = threadIdx.x; i < 16384; i += 1024) kb[i] = s[i];
}

// ------------------------- emit keypoints + scores (fp32) ------------------
__global__ void emit_k(const unsigned long long* __restrict__ keys,
                       float* __restrict__ kp, float* __restrict__ sc)
{
    int tid = blockIdx.x * 256 + threadIdx.x;      // 4 * 4096
    int b = tid >> 12;
    int r = tid & 4095;
    unsigned long long key = keys[(size_t)b * 16384 + r];
    unsigned idx = (unsigned)(key & 0xFFFFFFFFu);
    unsigned hi  = (unsigned)(key >> 32);
    unsigned sk  = ~hi;
    unsigned u   = (sk & 0x80000000u) ? (sk ^ 0x80000000u) : ~sk;
    float val = __uint_as_float(u);
    float tx = (float)(idx % 96);
    float ty = (float)(idx / 96);
    kp[(size_t)tid * 2 + 0] = tx;
    kp[(size_t)tid * 2 + 1] = ty;
    sc[tid] = val;
}

// --------------------- descriptor gather + L2 normalize (fp32) -------------
__global__ __launch_bounds__(256) void desc_out_k(const unsigned long long* __restrict__ keys,
                                                  const float* __restrict__ dm,
                                                  float* __restrict__ outd)
{
    int warp = threadIdx.x >> 6, lane = threadIdx.x & 63;
    int kpid = blockIdx.x * 4 + warp;              // 0..16383
    int b = kpid >> 12, r = kpid & 4095;
    unsigned long long key = keys[(size_t)b * 16384 + r];
    int idx = (int)(unsigned)(key & 0xFFFFFFFFu);
    float v = dm[((size_t)b * 64 + lane) * 9216 + idx];
    float ss = v * v;
#pragma unroll
    for (int o = 32; o > 0; o >>= 1) ss += __shfl_xor(ss, o, 64);
    float n = fmaxf(sqrtf(ss), 1e-12f);
    outd[(size_t)kpid * 64 + lane] = v / n;
}

// ---------------------------------------------------------------------------
extern "C" void kernel_launch(void* const* d_in, const int* in_sizes, int n_in,
                              void* d_out, int out_size, void* d_ws, size_t ws_size,
                              hipStream_t stream)
{
    const float* x      = (const float*)d_in[0];
    const float* w1     = (const float*)d_in[1];
    const float* g1     = (const float*)d_in[2];
    const float* b1     = (const float*)d_in[3];
    const float* w2     = (const float*)d_in[4];
    const float* g2     = (const float*)d_in[5];
    const float* b2     = (const float*)d_in[6];
    const float* w3     = (const float*)d_in[7];
    const float* g3     = (const float*)d_in[8];
    const float* b3     = (const float*)d_in[9];
    const float* w4     = (const float*)d_in[10];
    const float* g4     = (const float*)d_in[11];
    const float* b4     = (const float*)d_in[12];
    const float* wf     = (const float*)d_in[13];
    const float* bf     = (const float*)d_in[14];
    const float* det_w1 = (const float*)d_in[15];
    const float* det_b1 = (const float*)d_in[16];
    const float* det_g  = (const float*)d_in[17];
    const float* det_be = (const float*)d_in[18];
    const float* det_w2 = (const float*)d_in[19];
    const float* det_b2 = (const float*)d_in[20];
    const float* ds_w1  = (const float*)d_in[21];
    const float* ds_b1  = (const float*)d_in[22];
    const float* ds_g1  = (const float*)d_in[23];
    const float* ds_be1 = (const float*)d_in[24];
    const float* ds_w2  = (const float*)d_in[25];
    const float* ds_b2  = (const float*)d_in[26];
    const float* ds_g2  = (const float*)d_in[27];
    const float* ds_be2 = (const float*)d_in[28];

    char* ws = (char*)d_ws;
    // ---- misc persistent buffers at base [0, 819,968) ----
    float* scorem = (float*)(ws + 0);                              // [4,9216]
    unsigned long long* keys = (unsigned long long*)(ws + 147456); // [4,16384]
    float* wc  = (float*)(ws + 671744);                            // [64,64,9]
    float* pc  = (float*)(ws + 819200);                            // 768 B
    float* cbc = pc, *gc = pc + 64, *bec = pc + 128;
    const size_t B0 = 819968;

    pack_head_k<<<72, 256, 0, stream>>>(det_w1, det_b1, det_g, det_be,
                                        ds_w1, ds_b1, ds_g1, ds_be1,
                                        wc, cbc, gc, bec);

    float* desc_full;

    if (ws_size >= 59200000ull) {
        // =============== Layout A (peak 59,028,224 B) ======================
        float* c1pb  = (float*)(ws + B0);           // [32,386,386]   (phase 1)
        float* c2p   = (float*)(ws + 20488960);     // [4,64,194,194]
        float* c3p   = (float*)(ws + B0);           // [4,128,98,98]  (phase 2)
        float* c4    = (float*)(ws + 20488960);     // [4,256,96,96]  (phase 3)
        float* featp = (float*)(ws + B0);           // [4,64,98,98]   (phase 4)
        float* dd1   = (float*)(ws + 10654464);     // [4,64,96,96]
        desc_full    = (float*)(ws + 20488960);     // [4,64,96,96]

        zero_k<<<2048, 256, 0, stream>>>((float4*)(ws + B0), 3638016);

        for (int b = 0; b < 4; b++) {
            conv3x3b_k<3, 32, 4, 3, 384, 2, 1, 4, 1, 1, 1><<<96 * 8, 384, 0, stream>>>(
                x + (size_t)b * 3 * 768 * 768, w1, nullptr, g1, b1, c1pb);
            conv3x3p_k<32, 64, 4, 32, 192, 2, 1, 4, 1, 1, 1><<<48 * 16, 192, 0, stream>>>(
                c1pb, w2, nullptr, g2, b2, c2p + (size_t)b * 2408704);
        }
        zero_k<<<2048, 256, 0, stream>>>((float4*)(ws + B0), 1229312);
        conv3x3p_k<64, 128, 4, 32, 96, 2, 2, 4, 1, 1, 1><<<12 * 32 * 4, 192, 0, stream>>>(
            c2p, w3, nullptr, g3, b3, c3p);
        conv3x3p_k<128, 256, 4, 32, 96, 1, 2, 4, 1, 1, 0><<<12 * 64 * 4, 192, 0, stream>>>(
            c3p, w4, nullptr, g4, b4, c4);
        zero_k<<<2048, 256, 0, stream>>>((float4*)(ws + B0), 614656);
        conv1x1p_k<256, 64, 8, 64, 2, 4, 0, 0, 1><<<12 * 8 * 4, 192, 0, stream>>>(
            c4, wf, bf, nullptr, nullptr, featp, 256, 0);
        conv3x3p_k<64, 64, 4, 32, 96, 1, 2, 4, 1, 1, 0><<<12 * 16 * 4, 192, 0, stream>>>(
            featp, wc, cbc, gc, bec, dd1);
        conv1x1p_k<32, 1, 1, 32, 2, 4, 0, 0, 0><<<12 * 1 * 4, 192, 0, stream>>>(
            dd1, det_w2, det_b2, nullptr, nullptr, scorem, 64, 0);
        conv1x1p_k<32, 64, 8, 32, 2, 4, 0, 1, 0><<<12 * 8 * 4, 192, 0, stream>>>(
            dd1, ds_w2, ds_b2, ds_g2, ds_be2, desc_full, 64, 32);
    } else {
        // =============== Layout B (peak 57,443,072 B) ======================
        float* c3    = (float*)(ws + B0);           // [4,128,96,96] unpadded
        float* c1pb  = (float*)(ws + 19694336);     // [32,386,386]
        float* c2pb  = (float*)(ws + 38765824);     // [64,194,194]
        float* c4    = (float*)(ws + 19694336);     // [4,256,96,96]
        float* featp = (float*)(ws + B0);           // [4,64,98,98]
        float* dd1   = (float*)(ws + 10654464);     // [4,64,96,96]
        desc_full    = (float*)(ws + 20091648);     // [4,64,96,96]

        zero_k<<<2048, 256, 0, stream>>>((float4*)(ws + B0), 2973792);

        for (int b = 0; b < 4; b++) {
            conv3x3b_k<3, 32, 4, 3, 384, 2, 1, 4, 1, 1, 1><<<96 * 8, 384, 0, stream>>>(
                x + (size_t)b * 3 * 768 * 768, w1, nullptr, g1, b1, c1pb);
            conv3x3p_k<32, 64, 4, 32, 192, 2, 1, 4, 1, 1, 1><<<48 * 16, 192, 0, stream>>>(
                c1pb, w2, nullptr, g2, b2, c2pb);
            conv3x3p_k<64, 128, 4, 32, 96, 2, 2, 4, 1, 1, 0><<<12 * 32, 192, 0, stream>>>(
                c2pb, w3, nullptr, g3, b3, c3 + (size_t)b * 1179648);
        }
        conv3x3b_k<128, 256, 4, 32, 96, 1, 2, 4, 1, 1, 0><<<12 * 64 * 4, 192, 0, stream>>>(
            c3, w4, nullptr, g4, b4, c4);
        zero_k<<<2048, 256, 0, stream>>>((float4*)(ws + B0), 614656);
        conv1x1p_k<256, 64, 8, 64, 2, 4, 0, 0, 1><<<12 * 8 * 4, 192, 0, stream>>>(
            c4, wf, bf, nullptr, nullptr, featp, 256, 0);
        conv3x3p_k<64, 64, 4, 32, 96, 1, 2, 4, 1, 1, 0><<<12 * 16 * 4, 192, 0, stream>>>(
            featp, wc, cbc, gc, bec, dd1);
        conv1x1p_k<32, 1, 1, 32, 2, 4, 0, 0, 0><<<12 * 1 * 4, 192, 0, stream>>>(
            dd1, det_w2, det_b2, nullptr, nullptr, scorem, 64, 0);
        conv1x1p_k<32, 64, 8, 32, 2, 4, 0, 1, 0><<<12 * 8 * 4, 192, 0, stream>>>(
            dd1, ds_w2, ds_b2, ds_g2, ds_be2, desc_full, 64, 32);
    }

    nms_keys_k<<<256, 256, 0, stream>>>(scorem, keys);
    sort_k<<<4, 1024, 0, stream>>>(keys);

    float* out_kp = (float*)d_out;
    float* out_sc = out_kp + 4 * 4096 * 2;
    float* out_d  = out_sc + 4 * 4096;
    emit_k<<<64, 256, 0, stream>>>(keys, out_kp, out_sc);
    desc_out_k<<<4096, 256, 0, stream>>>(keys, desc_full, out_d);
}

// Round 15
// 1333.861 us; speedup vs baseline: 2.3626x; 1.0157x over previous
//
#include <hip/hip_runtime.h>

// ---------------------------------------------------------------------------
// XFeat detector: HYBRID accumulation everywhere.
// 3x3 convs: per-channel 9-tap fp32 dot + fp64 cross-channel sum (r14 proven).
// 1x1 convs (r15): 8-channel fp32 subgroup dot + fp64 cross-group sum.
// Channel order unchanged everywhere.
// Output (fp32): [kp 4*4096*2 | sc 4*4096 | d 4*4096*64]
// Layout A (ws>=59.2MB, peak 59.03MB) / B (peak 57,443,072 B).
// ---------------------------------------------------------------------------

#define EPS_BN 1e-5f

// ------------------------------ zero fill ----------------------------------
__global__ void zero_k(float4* __restrict__ p, size_t n)
{
    for (size_t i = (size_t)blockIdx.x * 256 + threadIdx.x; i < n;
         i += (size_t)gridDim.x * 256)
        p[i] = make_float4(0.f, 0.f, 0.f, 0.f);
}

// ---------- 3x3 conv, BOUNDS-CHECKED input (unpadded), hybrid acc ----------
template<int CIN,int COUT,int CPT,int CHUNK,int HOUT,int STRIDE,int TY,int P,
         int RELU,int BN,int PADOUT>
__global__ __launch_bounds__(HOUT*TY, 4)
void conv3x3b_k(const float* __restrict__ in, const float* __restrict__ wgt,
                const float* __restrict__ cbias, const float* __restrict__ gg,
                const float* __restrict__ bb, float* __restrict__ out)
{
    constexpr int HIN = HOUT * STRIDE;
    constexpr int NG  = COUT / CPT;
    constexpr int YB  = HOUT / (TY * P);
    constexpr int BLK = HOUT * TY;
    constexpr int NR  = (P - 1) * STRIDE + 3;
    static_assert(CIN % CHUNK == 0, "chunk");

    __shared__ float wl[CPT * CHUNK * 9];

    int bid = blockIdx.x;
    int yb  = bid % YB;  int r2 = bid / YB;
    int cog = r2 % NG;   int b  = r2 / NG;
    int tid = threadIdx.x;
    int x   = tid % HOUT;
    int ty  = tid / HOUT;
    int yo0 = (yb * TY + ty) * P;
    int cobase = cog * CPT;

    int xoff[3]; bool okx[3];
#pragma unroll
    for (int kx = 0; kx < 3; kx++) {
        int xi = STRIDE * x - 1 + kx;
        okx[kx]  = (xi >= 0) && (xi < HIN);
        xoff[kx] = min(max(xi, 0), HIN - 1);
    }
    int yoff[NR]; bool oky[NR];
#pragma unroll
    for (int r = 0; r < NR; r++) {
        int yi = STRIDE * yo0 - 1 + r;
        oky[r]  = (yi >= 0) && (yi < HIN);
        yoff[r] = min(max(yi, 0), HIN - 1) * HIN;
    }

    double acc[CPT][P];
#pragma unroll
    for (int co = 0; co < CPT; co++)
#pragma unroll
        for (int p = 0; p < P; p++) acc[co][p] = 0.0;

    const float* inb = in + (size_t)b * CIN * HIN * HIN;

    for (int c0 = 0; c0 < CIN; c0 += CHUNK) {
        __syncthreads();
        for (int i = tid; i < CPT * CHUNK * 9; i += BLK) {
            int k  = i % 9;
            int t2 = i / 9;
            int cc = t2 % CHUNK;
            int co = t2 / CHUNK;
            wl[i] = wgt[((size_t)(cobase + co) * CIN + (c0 + cc)) * 9 + k];
        }
        __syncthreads();

        for (int cc = 0; cc < CHUNK; cc++) {
            const float* inp = inb + (size_t)(c0 + cc) * HIN * HIN;
            float v[NR][3];
#pragma unroll
            for (int r = 0; r < NR; r++)
#pragma unroll
                for (int kx = 0; kx < 3; kx++) {
                    float t = inp[yoff[r] + xoff[kx]];
                    v[r][kx] = (oky[r] && okx[kx]) ? t : 0.0f;
                }
#pragma unroll
            for (int co = 0; co < CPT; co++) {
                const float* wp = &wl[(co * CHUNK + cc) * 9];
                float s[P];
#pragma unroll
                for (int p = 0; p < P; p++) s[p] = 0.0f;
#pragma unroll
                for (int ky = 0; ky < 3; ky++)
#pragma unroll
                    for (int kx = 0; kx < 3; kx++) {
                        float w = wp[ky * 3 + kx];
#pragma unroll
                        for (int p = 0; p < P; p++)
                            s[p] = fmaf(v[ky + p * STRIDE][kx], w, s[p]);
                    }
#pragma unroll
                for (int p = 0; p < P; p++) acc[co][p] += (double)s[p];
            }
        }
    }

    const float SQ = sqrtf(1.0f + EPS_BN);
    constexpr int WOUT = PADOUT ? HOUT + 2 : HOUT;
    size_t plane = (size_t)WOUT * WOUT;
    float* ob = out + ((size_t)b * COUT + cobase) * plane
              + (PADOUT ? ((size_t)(yo0 + 1) * WOUT + x + 1)
                        : ((size_t)yo0 * WOUT + x));
#pragma unroll
    for (int co = 0; co < CPT; co++) {
        float cb = cbias ? cbias[cobase + co] : 0.f;
#pragma unroll
        for (int p = 0; p < P; p++) {
            float a = (float)acc[co][p] + cb;
            float r;
            if (BN) r = gg[cobase + co] * (a / SQ) + bb[cobase + co];
            else    r = a;
            if (RELU) r = fmaxf(r, 0.f);
            ob[(size_t)co * plane + (size_t)p * WOUT] = r;
        }
    }
}

// ---------- 3x3 conv, PADDED input (no bounds), hybrid acc -----------------
template<int CIN,int COUT,int CPT,int CHUNK,int HOUT,int STRIDE,int TY,int P,
         int RELU,int BN,int PADOUT>
__global__ __launch_bounds__(HOUT*TY, 4)
void conv3x3p_k(const float* __restrict__ in, const float* __restrict__ wgt,
                const float* __restrict__ cbias, const float* __restrict__ gg,
                const float* __restrict__ bb, float* __restrict__ out)
{
    constexpr int HIN = HOUT * STRIDE;
    constexpr int PIN = HIN + 2;
    constexpr int NG  = COUT / CPT;
    constexpr int YB  = HOUT / (TY * P);
    constexpr int BLK = HOUT * TY;
    constexpr int NR  = (P - 1) * STRIDE + 3;
    constexpr size_t PIN2 = (size_t)PIN * PIN;
    static_assert(CIN % CHUNK == 0, "chunk");

    __shared__ float wl[CPT * CHUNK * 9];

    int bid = blockIdx.x;
    int yb  = bid % YB;  int r2 = bid / YB;
    int cog = r2 % NG;   int b  = r2 / NG;
    int tid = threadIdx.x;
    int x   = tid % HOUT;
    int ty  = tid / HOUT;
    int yo0 = (yb * TY + ty) * P;
    int cobase = cog * CPT;

    double acc[CPT][P];
#pragma unroll
    for (int co = 0; co < CPT; co++)
#pragma unroll
        for (int p = 0; p < P; p++) acc[co][p] = 0.0;

    const float* inb = in + (size_t)b * CIN * PIN2
                     + (size_t)(STRIDE * yo0) * PIN + STRIDE * x;

    for (int c0 = 0; c0 < CIN; c0 += CHUNK) {
        __syncthreads();
        for (int i = tid; i < CPT * CHUNK * 9; i += BLK) {
            int k  = i % 9;
            int t2 = i / 9;
            int cc = t2 % CHUNK;
            int co = t2 / CHUNK;
            wl[i] = wgt[((size_t)(cobase + co) * CIN + (c0 + cc)) * 9 + k];
        }
        __syncthreads();

        const float* ip = inb + (size_t)c0 * PIN2;
        for (int cc = 0; cc < CHUNK; cc++) {
            float v[NR][3];
#pragma unroll
            for (int r = 0; r < NR; r++)
#pragma unroll
                for (int kx = 0; kx < 3; kx++)
                    v[r][kx] = ip[(size_t)r * PIN + kx];
#pragma unroll
            for (int co = 0; co < CPT; co++) {
                const float* wp = &wl[(co * CHUNK + cc) * 9];
                float s[P];
#pragma unroll
                for (int p = 0; p < P; p++) s[p] = 0.0f;
#pragma unroll
                for (int ky = 0; ky < 3; ky++)
#pragma unroll
                    for (int kx = 0; kx < 3; kx++) {
                        float w = wp[ky * 3 + kx];
#pragma unroll
                        for (int p = 0; p < P; p++)
                            s[p] = fmaf(v[ky + p * STRIDE][kx], w, s[p]);
                    }
#pragma unroll
                for (int p = 0; p < P; p++) acc[co][p] += (double)s[p];
            }
            ip += PIN2;
        }
    }

    const float SQ = sqrtf(1.0f + EPS_BN);
    constexpr int WOUT = PADOUT ? HOUT + 2 : HOUT;
    size_t plane = (size_t)WOUT * WOUT;
    float* ob = out + ((size_t)b * COUT + cobase) * plane
              + (PADOUT ? ((size_t)(yo0 + 1) * WOUT + x + 1)
                        : ((size_t)yo0 * WOUT + x));
#pragma unroll
    for (int co = 0; co < CPT; co++) {
        float cb = cbias ? cbias[cobase + co] : 0.f;
#pragma unroll
        for (int p = 0; p < P; p++) {
            float a = (float)acc[co][p] + cb;
            float r;
            if (BN) r = gg[cobase + co] * (a / SQ) + bb[cobase + co];
            else    r = a;
            if (RELU) r = fmaxf(r, 0.f);
            ob[(size_t)co * plane + (size_t)p * WOUT] = r;
        }
    }
}

// -------- 1x1 conv: 8-ch fp32 subgroup dot + fp64 cross-group sum ----------
template<int CIN,int COUT,int CPT,int CHUNK,int TY,int P,int RELU,int BN,int PADOUT>
__global__ __launch_bounds__(96*TY, 4)
void conv1x1p_k(const float* __restrict__ in, const float* __restrict__ wgt,
                const float* __restrict__ cbias, const float* __restrict__ gg,
                const float* __restrict__ bb, float* __restrict__ out,
                int cin_tot, int cin_off)
{
    constexpr int HOUT = 96;
    constexpr int HW   = 96 * 96;
    constexpr int NG   = COUT / CPT;
    constexpr int YB   = HOUT / (TY * P);
    constexpr int BLK  = 96 * TY;
    constexpr int GC   = (CHUNK < 8) ? CHUNK : 8;
    static_assert(CHUNK % GC == 0, "gc");

    __shared__ float wl[CPT * CHUNK];

    int bid = blockIdx.x;
    int yb  = bid % YB;  int r2 = bid / YB;
    int cog = r2 % NG;   int b  = r2 / NG;
    int tid = threadIdx.x;
    int x   = tid % HOUT;
    int ty  = tid / HOUT;
    int yo0 = (yb * TY + ty) * P;
    int cobase = cog * CPT;

    double acc[CPT][P];
#pragma unroll
    for (int co = 0; co < CPT; co++)
#pragma unroll
        for (int p = 0; p < P; p++) acc[co][p] = 0.0;

    const float* inb = in + ((size_t)b * cin_tot + cin_off) * HW + (size_t)yo0 * HOUT + x;

    for (int c0 = 0; c0 < CIN; c0 += CHUNK) {
        __syncthreads();
        for (int i = tid; i < CPT * CHUNK; i += BLK) {
            int cc = i % CHUNK;
            int co = i / CHUNK;
            wl[i] = wgt[(size_t)(cobase + co) * CIN + (c0 + cc)];
        }
        __syncthreads();
        for (int cg = 0; cg < CHUNK; cg += GC) {
            float s[CPT][P];
#pragma unroll
            for (int co = 0; co < CPT; co++)
#pragma unroll
                for (int p = 0; p < P; p++) s[co][p] = 0.0f;
#pragma unroll
            for (int cc = cg; cc < cg + GC; cc++) {
                const float* inp = inb + (size_t)(c0 + cc) * HW;
                float v[P];
#pragma unroll
                for (int p = 0; p < P; p++) v[p] = inp[p * HOUT];
#pragma unroll
                for (int co = 0; co < CPT; co++) {
                    float w = wl[co * CHUNK + cc];
#pragma unroll
                    for (int p = 0; p < P; p++) s[co][p] = fmaf(v[p], w, s[co][p]);
                }
            }
#pragma unroll
            for (int co = 0; co < CPT; co++)
#pragma unroll
                for (int p = 0; p < P; p++) acc[co][p] += (double)s[co][p];
        }
    }

    const float SQ = sqrtf(1.0f + EPS_BN);
    constexpr int WOUT = PADOUT ? 98 : 96;
    size_t plane = (size_t)WOUT * WOUT;
    float* ob = out + ((size_t)b * COUT + cobase) * plane
              + (PADOUT ? ((size_t)(yo0 + 1) * WOUT + x + 1)
                        : ((size_t)yo0 * WOUT + x));
#pragma unroll
    for (int co = 0; co < CPT; co++) {
        float cb = cbias ? cbias[cobase + co] : 0.f;
#pragma unroll
        for (int p = 0; p < P; p++) {
            float a = (float)acc[co][p] + cb;
            float r;
            if (BN) r = gg[cobase + co] * (a / SQ) + bb[cobase + co];
            else    r = a;
            if (RELU) r = fmaxf(r, 0.f);
            ob[(size_t)co * plane + (size_t)p * WOUT] = r;
        }
    }
}

// --------------- pack det/desc head-1 weights into one 64-ch conv ----------
__global__ void pack_head_k(const float* __restrict__ dw, const float* __restrict__ db,
                            const float* __restrict__ dg, const float* __restrict__ dbe,
                            const float* __restrict__ sw, const float* __restrict__ sb,
                            const float* __restrict__ sg, const float* __restrict__ sbe,
                            float* __restrict__ wc, float* __restrict__ cbc,
                            float* __restrict__ gc, float* __restrict__ bec)
{
    int i = blockIdx.x * 256 + threadIdx.x;
    const int WN = 32 * 64 * 9;
    if (i < WN) { wc[i] = dw[i]; wc[WN + i] = sw[i]; }
    if (i < 32) {
        cbc[i] = db[i]; cbc[32 + i] = sb[i];
        gc[i]  = dg[i]; gc[32 + i]  = sg[i];
        bec[i] = dbe[i]; bec[32 + i] = sbe[i];
    }
}

// ------------------------- NMS + sortable key build ------------------------
__global__ void nms_keys_k(const float* __restrict__ score, unsigned long long* __restrict__ keys)
{
    int tid = blockIdx.x * 256 + threadIdx.x;      // 4 * 16384
    int b = tid >> 14;
    int i = tid & 16383;
    unsigned long long key = ~0ULL;                // padding sorts last
    if (i < 9216) {
        int y = i / 96, x = i % 96;
        const float* sb = score + (size_t)b * 9216;
        float s = sb[i];
        float m = -INFINITY;
#pragma unroll
        for (int dy = -2; dy <= 1; dy++) {
            int yy = y + dy;
            if (yy < 0 || yy >= 96) continue;
#pragma unroll
            for (int dx = -2; dx <= 1; dx++) {
                int xx = x + dx;
                if (xx < 0 || xx >= 96) continue;
                m = fmaxf(m, sb[yy * 96 + xx]);
            }
        }
        float nv = (s == m) ? s : 0.0f;
        if (nv == 0.0f) nv = 0.0f;                 // canonicalize -0.0 -> +0.0
        unsigned u = __float_as_uint(nv);
        unsigned sk = (u & 0x80000000u) ? ~u : (u | 0x80000000u);
        key = ((unsigned long long)(~sk) << 32) | (unsigned)i;
    }
    keys[(size_t)b * 16384 + i] = key;
}

// ------------------------- bitonic sort (per batch) ------------------------
__global__ __launch_bounds__(1024) void sort_k(unsigned long long* __restrict__ keys)
{
    __shared__ unsigned long long s[16384];
    unsigned long long* kb = keys + (size_t)blockIdx.x * 16384;
    for (int i = threadIdx.x; i < 16384; i += 1024) s[i] = kb[i];
    __syncthreads();
    for (int k = 2; k <= 16384; k <<= 1) {
        for (int j = k >> 1; j > 0; j >>= 1) {
            for (int i = threadIdx.x; i < 16384; i += 1024) {
                int ixj = i ^ j;
                if (ixj > i) {
                    unsigned long long a = s[i], c = s[ixj];
                    bool up = ((i & k) == 0);
                    if ((a > c) == up) { s[i] = c; s[ixj] = a; }
                }
            }
            __syncthreads();
        }
    }
    for (int i = threadIdx.x; i < 16384; i += 1024) kb[i] = s[i];
}

// ------------------------- emit keypoints + scores (fp32) ------------------
__global__ void emit_k(const unsigned long long* __restrict__ keys,
                       float* __restrict__ kp, float* __restrict__ sc)
{
    int tid = blockIdx.x * 256 + threadIdx.x;      // 4 * 4096
    int b = tid >> 12;
    int r = tid & 4095;
    unsigned long long key = keys[(size_t)b * 16384 + r];
    unsigned idx = (unsigned)(key & 0xFFFFFFFFu);
    unsigned hi  = (unsigned)(key >> 32);
    unsigned sk  = ~hi;
    unsigned u   = (sk & 0x80000000u) ? (sk ^ 0x80000000u) : ~sk;
    float val = __uint_as_float(u);
    float tx = (float)(idx % 96);
    float ty = (float)(idx / 96);
    kp[(size_t)tid * 2 + 0] = tx;
    kp[(size_t)tid * 2 + 1] = ty;
    sc[tid] = val;
}

// --------------------- descriptor gather + L2 normalize (fp32) -------------
__global__ __launch_bounds__(256) void desc_out_k(const unsigned long long* __restrict__ keys,
                                                  const float* __restrict__ dm,
                                                  float* __restrict__ outd)
{
    int warp = threadIdx.x >> 6, lane = threadIdx.x & 63;
    int kpid = blockIdx.x * 4 + warp;              // 0..16383
    int b = kpid >> 12, r = kpid & 4095;
    unsigned long long key = keys[(size_t)b * 16384 + r];
    int idx = (int)(unsigned)(key & 0xFFFFFFFFu);
    float v = dm[((size_t)b * 64 + lane) * 9216 + idx];
    float ss = v * v;
#pragma unroll
    for (int o = 32; o > 0; o >>= 1) ss += __shfl_xor(ss, o, 64);
    float n = fmaxf(sqrtf(ss), 1e-12f);
    outd[(size_t)kpid * 64 + lane] = v / n;
}

// ---------------------------------------------------------------------------
extern "C" void kernel_launch(void* const* d_in, const int* in_sizes, int n_in,
                              void* d_out, int out_size, void* d_ws, size_t ws_size,
                              hipStream_t stream)
{
    const float* x      = (const float*)d_in[0];
    const float* w1     = (const float*)d_in[1];
    const float* g1     = (const float*)d_in[2];
    const float* b1     = (const float*)d_in[3];
    const float* w2     = (const float*)d_in[4];
    const float* g2     = (const float*)d_in[5];
    const float* b2     = (const float*)d_in[6];
    const float* w3     = (const float*)d_in[7];
    const float* g3     = (const float*)d_in[8];
    const float* b3     = (const float*)d_in[9];
    const float* w4     = (const float*)d_in[10];
    const float* g4     = (const float*)d_in[11];
    const float* b4     = (const float*)d_in[12];
    const float* wf     = (const float*)d_in[13];
    const float* bf     = (const float*)d_in[14];
    const float* det_w1 = (const float*)d_in[15];
    const float* det_b1 = (const float*)d_in[16];
    const float* det_g  = (const float*)d_in[17];
    const float* det_be = (const float*)d_in[18];
    const float* det_w2 = (const float*)d_in[19];
    const float* det_b2 = (const float*)d_in[20];
    const float* ds_w1  = (const float*)d_in[21];
    const float* ds_b1  = (const float*)d_in[22];
    const float* ds_g1  = (const float*)d_in[23];
    const float* ds_be1 = (const float*)d_in[24];
    const float* ds_w2  = (const float*)d_in[25];
    const float* ds_b2  = (const float*)d_in[26];
    const float* ds_g2  = (const float*)d_in[27];
    const float* ds_be2 = (const float*)d_in[28];

    char* ws = (char*)d_ws;
    // ---- misc persistent buffers at base [0, 819,968) ----
    float* scorem = (float*)(ws + 0);                              // [4,9216]
    unsigned long long* keys = (unsigned long long*)(ws + 147456); // [4,16384]
    float* wc  = (float*)(ws + 671744);                            // [64,64,9]
    float* pc  = (float*)(ws + 819200);                            // 768 B
    float* cbc = pc, *gc = pc + 64, *bec = pc + 128;
    const size_t B0 = 819968;

    pack_head_k<<<72, 256, 0, stream>>>(det_w1, det_b1, det_g, det_be,
                                        ds_w1, ds_b1, ds_g1, ds_be1,
                                        wc, cbc, gc, bec);

    float* desc_full;

    if (ws_size >= 59200000ull) {
        // =============== Layout A (peak 59,028,224 B) ======================
        float* c1pb  = (float*)(ws + B0);           // [32,386,386]   (phase 1)
        float* c2p   = (float*)(ws + 20488960);     // [4,64,194,194]
        float* c3p   = (float*)(ws + B0);           // [4,128,98,98]  (phase 2)
        float* c4    = (float*)(ws + 20488960);     // [4,256,96,96]  (phase 3)
        float* featp = (float*)(ws + B0);           // [4,64,98,98]   (phase 4)
        float* dd1   = (float*)(ws + 10654464);     // [4,64,96,96]
        desc_full    = (float*)(ws + 20488960);     // [4,64,96,96]

        zero_k<<<2048, 256, 0, stream>>>((float4*)(ws + B0), 3638016);

        for (int b = 0; b < 4; b++) {
            conv3x3b_k<3, 32, 4, 3, 384, 2, 1, 4, 1, 1, 1><<<96 * 8, 384, 0, stream>>>(
                x + (size_t)b * 3 * 768 * 768, w1, nullptr, g1, b1, c1pb);
            conv3x3p_k<32, 64, 4, 32, 192, 2, 1, 4, 1, 1, 1><<<48 * 16, 192, 0, stream>>>(
                c1pb, w2, nullptr, g2, b2, c2p + (size_t)b * 2408704);
        }
        zero_k<<<2048, 256, 0, stream>>>((float4*)(ws + B0), 1229312);
        conv3x3p_k<64, 128, 4, 32, 96, 2, 2, 4, 1, 1, 1><<<12 * 32 * 4, 192, 0, stream>>>(
            c2p, w3, nullptr, g3, b3, c3p);
        conv3x3p_k<128, 256, 4, 32, 96, 1, 2, 4, 1, 1, 0><<<12 * 64 * 4, 192, 0, stream>>>(
            c3p, w4, nullptr, g4, b4, c4);
        zero_k<<<2048, 256, 0, stream>>>((float4*)(ws + B0), 614656);
        conv1x1p_k<256, 64, 8, 64, 2, 4, 0, 0, 1><<<12 * 8 * 4, 192, 0, stream>>>(
            c4, wf, bf, nullptr, nullptr, featp, 256, 0);
        conv3x3p_k<64, 64, 4, 32, 96, 1, 2, 4, 1, 1, 0><<<12 * 16 * 4, 192, 0, stream>>>(
            featp, wc, cbc, gc, bec, dd1);
        conv1x1p_k<32, 1, 1, 32, 2, 4, 0, 0, 0><<<12 * 1 * 4, 192, 0, stream>>>(
            dd1, det_w2, det_b2, nullptr, nullptr, scorem, 64, 0);
        conv1x1p_k<32, 64, 8, 32, 2, 4, 0, 1, 0><<<12 * 8 * 4, 192, 0, stream>>>(
            dd1, ds_w2, ds_b2, ds_g2, ds_be2, desc_full, 64, 32);
    } else {
        // =============== Layout B (peak 57,443,072 B) ======================
        float* c3    = (float*)(ws + B0);           // [4,128,96,96] unpadded
        float* c1pb  = (float*)(ws + 19694336);     // [32,386,386]
        float* c2pb  = (float*)(ws + 38765824);     // [64,194,194]
        float* c4    = (float*)(ws + 19694336);     // [4,256,96,96]
        float* featp = (float*)(ws + B0);           // [4,64,98,98]
        float* dd1   = (float*)(ws + 10654464);     // [4,64,96,96]
        desc_full    = (float*)(ws + 20091648);     // [4,64,96,96]

        zero_k<<<2048, 256, 0, stream>>>((float4*)(ws + B0), 2973792);

        for (int b = 0; b < 4; b++) {
            conv3x3b_k<3, 32, 4, 3, 384, 2, 1, 4, 1, 1, 1><<<96 * 8, 384, 0, stream>>>(
                x + (size_t)b * 3 * 768 * 768, w1, nullptr, g1, b1, c1pb);
            conv3x3p_k<32, 64, 4, 32, 192, 2, 1, 4, 1, 1, 1><<<48 * 16, 192, 0, stream>>>(
                c1pb, w2, nullptr, g2, b2, c2pb);
            conv3x3p_k<64, 128, 4, 32, 96, 2, 2, 4, 1, 1, 0><<<12 * 32, 192, 0, stream>>>(
                c2pb, w3, nullptr, g3, b3, c3 + (size_t)b * 1179648);
        }
        conv3x3b_k<128, 256, 4, 32, 96, 1, 2, 4, 1, 1, 0><<<12 * 64 * 4, 192, 0, stream>>>(
            c3, w4, nullptr, g4, b4, c4);
        zero_k<<<2048, 256, 0, stream>>>((float4*)(ws + B0), 614656);
        conv1x1p_k<256, 64, 8, 64, 2, 4, 0, 0, 1><<<12 * 8 * 4, 192, 0, stream>>>(
            c4, wf, bf, nullptr, nullptr, featp, 256, 0);
        conv3x3p_k<64, 64, 4, 32, 96, 1, 2, 4, 1, 1, 0><<<12 * 16 * 4, 192, 0, stream>>>(
            featp, wc, cbc, gc, bec, dd1);
        conv1x1p_k<32, 1, 1, 32, 2, 4, 0, 0, 0><<<12 * 1 * 4, 192, 0, stream>>>(
            dd1, det_w2, det_b2, nullptr, nullptr, scorem, 64, 0);
        conv1x1p_k<32, 64, 8, 32, 2, 4, 0, 1, 0><<<12 * 8 * 4, 192, 0, stream>>>(
            dd1, ds_w2, ds_b2, ds_g2, ds_be2, desc_full, 64, 32);
    }

    nms_keys_k<<<256, 256, 0, stream>>>(scorem, keys);
    sort_k<<<4, 1024, 0, stream>>>(keys);

    float* out_kp = (float*)d_out;
    float* out_sc = out_kp + 4 * 4096 * 2;
    float* out_d  = out_sc + 4 * 4096;
    emit_k<<<64, 256, 0, stream>>>(keys, out_kp, out_sc);
    desc_out_k<<<4096, 256, 0, stream>>>(keys, desc_full, out_d);
}

// Round 17
// 1301.027 us; speedup vs baseline: 2.4222x; 1.0252x over previous
//
#include <hip/hip_runtime.h>

// ---------------------------------------------------------------------------
// XFeat detector: HYBRID accumulation, 4-channel fp32 groups (r16).
// 3x3 convs: 4-channel (36-tap) fp32 group dot + fp64 cross-group sum.
// 1x1 convs: 8-channel fp32 subgroup dot + fp64 cross-group sum (r15 proven).
// Channel order unchanged everywhere. Score noise ~3e-7 rel (r6's failing
// all-fp32 was ~30x worse; r14/r15 hybrids passed with identical ranking).
// Output (fp32): [kp 4*4096*2 | sc 4*4096 | d 4*4096*64]
// Layout A (ws>=59.2MB, peak 59.03MB) / B (peak 57,443,072 B).
// ---------------------------------------------------------------------------

#define EPS_BN 1e-5f

// ------------------------------ zero fill ----------------------------------
__global__ void zero_k(float4* __restrict__ p, size_t n)
{
    for (size_t i = (size_t)blockIdx.x * 256 + threadIdx.x; i < n;
         i += (size_t)gridDim.x * 256)
        p[i] = make_float4(0.f, 0.f, 0.f, 0.f);
}

// ---------- 3x3 conv, BOUNDS-CHECKED input (unpadded), hybrid acc ----------
template<int CIN,int COUT,int CPT,int CHUNK,int HOUT,int STRIDE,int TY,int P,
         int RELU,int BN,int PADOUT>
__global__ __launch_bounds__(HOUT*TY, 4)
void conv3x3b_k(const float* __restrict__ in, const float* __restrict__ wgt,
                const float* __restrict__ cbias, const float* __restrict__ gg,
                const float* __restrict__ bb, float* __restrict__ out)
{
    constexpr int HIN = HOUT * STRIDE;
    constexpr int NG  = COUT / CPT;
    constexpr int YB  = HOUT / (TY * P);
    constexpr int BLK = HOUT * TY;
    constexpr int NR  = (P - 1) * STRIDE + 3;
    constexpr int GC  = (CHUNK % 4 == 0) ? 4 : CHUNK;
    static_assert(CIN % CHUNK == 0, "chunk");
    static_assert(CHUNK % GC == 0, "gc");

    __shared__ float wl[CPT * CHUNK * 9];

    int bid = blockIdx.x;
    int yb  = bid % YB;  int r2 = bid / YB;
    int cog = r2 % NG;   int b  = r2 / NG;
    int tid = threadIdx.x;
    int x   = tid % HOUT;
    int ty  = tid / HOUT;
    int yo0 = (yb * TY + ty) * P;
    int cobase = cog * CPT;

    int xoff[3]; bool okx[3];
#pragma unroll
    for (int kx = 0; kx < 3; kx++) {
        int xi = STRIDE * x - 1 + kx;
        okx[kx]  = (xi >= 0) && (xi < HIN);
        xoff[kx] = min(max(xi, 0), HIN - 1);
    }
    int yoff[NR]; bool oky[NR];
#pragma unroll
    for (int r = 0; r < NR; r++) {
        int yi = STRIDE * yo0 - 1 + r;
        oky[r]  = (yi >= 0) && (yi < HIN);
        yoff[r] = min(max(yi, 0), HIN - 1) * HIN;
    }

    double acc[CPT][P];
#pragma unroll
    for (int co = 0; co < CPT; co++)
#pragma unroll
        for (int p = 0; p < P; p++) acc[co][p] = 0.0;

    const float* inb = in + (size_t)b * CIN * HIN * HIN;

    for (int c0 = 0; c0 < CIN; c0 += CHUNK) {
        __syncthreads();
        for (int i = tid; i < CPT * CHUNK * 9; i += BLK) {
            int k  = i % 9;
            int t2 = i / 9;
            int cc = t2 % CHUNK;
            int co = t2 / CHUNK;
            wl[i] = wgt[((size_t)(cobase + co) * CIN + (c0 + cc)) * 9 + k];
        }
        __syncthreads();

        for (int cg = 0; cg < CHUNK; cg += GC) {
            float s[CPT][P];
#pragma unroll
            for (int co = 0; co < CPT; co++)
#pragma unroll
                for (int p = 0; p < P; p++) s[co][p] = 0.0f;
#pragma unroll
            for (int cc = cg; cc < cg + GC; cc++) {
                const float* inp = inb + (size_t)(c0 + cc) * HIN * HIN;
                float v[NR][3];
#pragma unroll
                for (int r = 0; r < NR; r++)
#pragma unroll
                    for (int kx = 0; kx < 3; kx++) {
                        float t = inp[yoff[r] + xoff[kx]];
                        v[r][kx] = (oky[r] && okx[kx]) ? t : 0.0f;
                    }
#pragma unroll
                for (int co = 0; co < CPT; co++) {
                    const float* wp = &wl[(co * CHUNK + cc) * 9];
#pragma unroll
                    for (int ky = 0; ky < 3; ky++)
#pragma unroll
                        for (int kx = 0; kx < 3; kx++) {
                            float w = wp[ky * 3 + kx];
#pragma unroll
                            for (int p = 0; p < P; p++)
                                s[co][p] = fmaf(v[ky + p * STRIDE][kx], w, s[co][p]);
                        }
                }
            }
#pragma unroll
            for (int co = 0; co < CPT; co++)
#pragma unroll
                for (int p = 0; p < P; p++) acc[co][p] += (double)s[co][p];
        }
    }

    const float SQ = sqrtf(1.0f + EPS_BN);
    constexpr int WOUT = PADOUT ? HOUT + 2 : HOUT;
    size_t plane = (size_t)WOUT * WOUT;
    float* ob = out + ((size_t)b * COUT + cobase) * plane
              + (PADOUT ? ((size_t)(yo0 + 1) * WOUT + x + 1)
                        : ((size_t)yo0 * WOUT + x));
#pragma unroll
    for (int co = 0; co < CPT; co++) {
        float cb = cbias ? cbias[cobase + co] : 0.f;
#pragma unroll
        for (int p = 0; p < P; p++) {
            float a = (float)acc[co][p] + cb;
            float r;
            if (BN) r = gg[cobase + co] * (a / SQ) + bb[cobase + co];
            else    r = a;
            if (RELU) r = fmaxf(r, 0.f);
            ob[(size_t)co * plane + (size_t)p * WOUT] = r;
        }
    }
}

// ---------- 3x3 conv, PADDED input (no bounds), hybrid acc -----------------
template<int CIN,int COUT,int CPT,int CHUNK,int HOUT,int STRIDE,int TY,int P,
         int RELU,int BN,int PADOUT>
__global__ __launch_bounds__(HOUT*TY, 4)
void conv3x3p_k(const float* __restrict__ in, const float* __restrict__ wgt,
                const float* __restrict__ cbias, const float* __restrict__ gg,
                const float* __restrict__ bb, float* __restrict__ out)
{
    constexpr int HIN = HOUT * STRIDE;
    constexpr int PIN = HIN + 2;
    constexpr int NG  = COUT / CPT;
    constexpr int YB  = HOUT / (TY * P);
    constexpr int BLK = HOUT * TY;
    constexpr int NR  = (P - 1) * STRIDE + 3;
    constexpr size_t PIN2 = (size_t)PIN * PIN;
    constexpr int GC  = (CHUNK % 4 == 0) ? 4 : CHUNK;
    static_assert(CIN % CHUNK == 0, "chunk");
    static_assert(CHUNK % GC == 0, "gc");

    __shared__ float wl[CPT * CHUNK * 9];

    int bid = blockIdx.x;
    int yb  = bid % YB;  int r2 = bid / YB;
    int cog = r2 % NG;   int b  = r2 / NG;
    int tid = threadIdx.x;
    int x   = tid % HOUT;
    int ty  = tid / HOUT;
    int yo0 = (yb * TY + ty) * P;
    int cobase = cog * CPT;

    double acc[CPT][P];
#pragma unroll
    for (int co = 0; co < CPT; co++)
#pragma unroll
        for (int p = 0; p < P; p++) acc[co][p] = 0.0;

    const float* inb = in + (size_t)b * CIN * PIN2
                     + (size_t)(STRIDE * yo0) * PIN + STRIDE * x;

    for (int c0 = 0; c0 < CIN; c0 += CHUNK) {
        __syncthreads();
        for (int i = tid; i < CPT * CHUNK * 9; i += BLK) {
            int k  = i % 9;
            int t2 = i / 9;
            int cc = t2 % CHUNK;
            int co = t2 / CHUNK;
            wl[i] = wgt[((size_t)(cobase + co) * CIN + (c0 + cc)) * 9 + k];
        }
        __syncthreads();

        for (int cg = 0; cg < CHUNK; cg += GC) {
            float s[CPT][P];
#pragma unroll
            for (int co = 0; co < CPT; co++)
#pragma unroll
                for (int p = 0; p < P; p++) s[co][p] = 0.0f;
            const float* ip = inb + (size_t)(c0 + cg) * PIN2;
#pragma unroll
            for (int cc = cg; cc < cg + GC; cc++) {
                float v[NR][3];
#pragma unroll
                for (int r = 0; r < NR; r++)
#pragma unroll
                    for (int kx = 0; kx < 3; kx++)
                        v[r][kx] = ip[(size_t)r * PIN + kx];
#pragma unroll
                for (int co = 0; co < CPT; co++) {
                    const float* wp = &wl[(co * CHUNK + cc) * 9];
#pragma unroll
                    for (int ky = 0; ky < 3; ky++)
#pragma unroll
                        for (int kx = 0; kx < 3; kx++) {
                            float w = wp[ky * 3 + kx];
#pragma unroll
                            for (int p = 0; p < P; p++)
                                s[co][p] = fmaf(v[ky + p * STRIDE][kx], w, s[co][p]);
                        }
                }
                ip += PIN2;
            }
#pragma unroll
            for (int co = 0; co < CPT; co++)
#pragma unroll
                for (int p = 0; p < P; p++) acc[co][p] += (double)s[co][p];
        }
    }

    const float SQ = sqrtf(1.0f + EPS_BN);
    constexpr int WOUT = PADOUT ? HOUT + 2 : HOUT;
    size_t plane = (size_t)WOUT * WOUT;
    float* ob = out + ((size_t)b * COUT + cobase) * plane
              + (PADOUT ? ((size_t)(yo0 + 1) * WOUT + x + 1)
                        : ((size_t)yo0 * WOUT + x));
#pragma unroll
    for (int co = 0; co < CPT; co++) {
        float cb = cbias ? cbias[cobase + co] : 0.f;
#pragma unroll
        for (int p = 0; p < P; p++) {
            float a = (float)acc[co][p] + cb;
            float r;
            if (BN) r = gg[cobase + co] * (a / SQ) + bb[cobase + co];
            else    r = a;
            if (RELU) r = fmaxf(r, 0.f);
            ob[(size_t)co * plane + (size_t)p * WOUT] = r;
        }
    }
}

// -------- 1x1 conv: 8-ch fp32 subgroup dot + fp64 cross-group sum ----------
template<int CIN,int COUT,int CPT,int CHUNK,int TY,int P,int RELU,int BN,int PADOUT>
__global__ __launch_bounds__(96*TY, 4)
void conv1x1p_k(const float* __restrict__ in, const float* __restrict__ wgt,
                const float* __restrict__ cbias, const float* __restrict__ gg,
                const float* __restrict__ bb, float* __restrict__ out,
                int cin_tot, int cin_off)
{
    constexpr int HOUT = 96;
    constexpr int HW   = 96 * 96;
    constexpr int NG   = COUT / CPT;
    constexpr int YB   = HOUT / (TY * P);
    constexpr int BLK  = 96 * TY;
    constexpr int GC   = (CHUNK < 8) ? CHUNK : 8;
    static_assert(CHUNK % GC == 0, "gc");

    __shared__ float wl[CPT * CHUNK];

    int bid = blockIdx.x;
    int yb  = bid % YB;  int r2 = bid / YB;
    int cog = r2 % NG;   int b  = r2 / NG;
    int tid = threadIdx.x;
    int x   = tid % HOUT;
    int ty  = tid / HOUT;
    int yo0 = (yb * TY + ty) * P;
    int cobase = cog * CPT;

    double acc[CPT][P];
#pragma unroll
    for (int co = 0; co < CPT; co++)
#pragma unroll
        for (int p = 0; p < P; p++) acc[co][p] = 0.0;

    const float* inb = in + ((size_t)b * cin_tot + cin_off) * HW + (size_t)yo0 * HOUT + x;

    for (int c0 = 0; c0 < CIN; c0 += CHUNK) {
        __syncthreads();
        for (int i = tid; i < CPT * CHUNK; i += BLK) {
            int cc = i % CHUNK;
            int co = i / CHUNK;
            wl[i] = wgt[(size_t)(cobase + co) * CIN + (c0 + cc)];
        }
        __syncthreads();
        for (int cg = 0; cg < CHUNK; cg += GC) {
            float s[CPT][P];
#pragma unroll
            for (int co = 0; co < CPT; co++)
#pragma unroll
                for (int p = 0; p < P; p++) s[co][p] = 0.0f;
#pragma unroll
            for (int cc = cg; cc < cg + GC; cc++) {
                const float* inp = inb + (size_t)(c0 + cc) * HW;
                float v[P];
#pragma unroll
                for (int p = 0; p < P; p++) v[p] = inp[p * HOUT];
#pragma unroll
                for (int co = 0; co < CPT; co++) {
                    float w = wl[co * CHUNK + cc];
#pragma unroll
                    for (int p = 0; p < P; p++) s[co][p] = fmaf(v[p], w, s[co][p]);
                }
            }
#pragma unroll
            for (int co = 0; co < CPT; co++)
#pragma unroll
                for (int p = 0; p < P; p++) acc[co][p] += (double)s[co][p];
        }
    }

    const float SQ = sqrtf(1.0f + EPS_BN);
    constexpr int WOUT = PADOUT ? 98 : 96;
    size_t plane = (size_t)WOUT * WOUT;
    float* ob = out + ((size_t)b * COUT + cobase) * plane
              + (PADOUT ? ((size_t)(yo0 + 1) * WOUT + x + 1)
                        : ((size_t)yo0 * WOUT + x));
#pragma unroll
    for (int co = 0; co < CPT; co++) {
        float cb = cbias ? cbias[cobase + co] : 0.f;
#pragma unroll
        for (int p = 0; p < P; p++) {
            float a = (float)acc[co][p] + cb;
            float r;
            if (BN) r = gg[cobase + co] * (a / SQ) + bb[cobase + co];
            else    r = a;
            if (RELU) r = fmaxf(r, 0.f);
            ob[(size_t)co * plane + (size_t)p * WOUT] = r;
        }
    }
}

// --------------- pack det/desc head-1 weights into one 64-ch conv ----------
__global__ void pack_head_k(const float* __restrict__ dw, const float* __restrict__ db,
                            const float* __restrict__ dg, const float* __restrict__ dbe,
                            const float* __restrict__ sw, const float* __restrict__ sb,
                            const float* __restrict__ sg, const float* __restrict__ sbe,
                            float* __restrict__ wc, float* __restrict__ cbc,
                            float* __restrict__ gc, float* __restrict__ bec)
{
    int i = blockIdx.x * 256 + threadIdx.x;
    const int WN = 32 * 64 * 9;
    if (i < WN) { wc[i] = dw[i]; wc[WN + i] = sw[i]; }
    if (i < 32) {
        cbc[i] = db[i]; cbc[32 + i] = sb[i];
        gc[i]  = dg[i]; gc[32 + i]  = sg[i];
        bec[i] = dbe[i]; bec[32 + i] = sbe[i];
    }
}

// ------------------------- NMS + sortable key build ------------------------
__global__ void nms_keys_k(const float* __restrict__ score, unsigned long long* __restrict__ keys)
{
    int tid = blockIdx.x * 256 + threadIdx.x;      // 4 * 16384
    int b = tid >> 14;
    int i = tid & 16383;
    unsigned long long key = ~0ULL;                // padding sorts last
    if (i < 9216) {
        int y = i / 96, x = i % 96;
        const float* sb = score + (size_t)b * 9216;
        float s = sb[i];
        float m = -INFINITY;
#pragma unroll
        for (int dy = -2; dy <= 1; dy++) {
            int yy = y + dy;
            if (yy < 0 || yy >= 96) continue;
#pragma unroll
            for (int dx = -2; dx <= 1; dx++) {
                int xx = x + dx;
                if (xx < 0 || xx >= 96) continue;
                m = fmaxf(m, sb[yy * 96 + xx]);
            }
        }
        float nv = (s == m) ? s : 0.0f;
        if (nv == 0.0f) nv = 0.0f;                 // canonicalize -0.0 -> +0.0
        unsigned u = __float_as_uint(nv);
        unsigned sk = (u & 0x80000000u) ? ~u : (u | 0x80000000u);
        key = ((unsigned long long)(~sk) << 32) | (unsigned)i;
    }
    keys[(size_t)b * 16384 + i] = key;
}

// ------------------------- bitonic sort (per batch) ------------------------
__global__ __launch_bounds__(1024) void sort_k(unsigned long long* __restrict__ keys)
{
    __shared__ unsigned long long s[16384];
    unsigned long long* kb = keys + (size_t)blockIdx.x * 16384;
    for (int i = threadIdx.x; i < 16384; i += 1024) s[i] = kb[i];
    __syncthreads();
    for (int k = 2; k <= 16384; k <<= 1) {
        for (int j = k >> 1; j > 0; j >>= 1) {
            for (int i = threadIdx.x; i < 16384; i += 1024) {
                int ixj = i ^ j;
                if (ixj > i) {
                    unsigned long long a = s[i], c = s[ixj];
                    bool up = ((i & k) == 0);
                    if ((a > c) == up) { s[i] = c; s[ixj] = a; }
                }
            }
            __syncthreads();
        }
    }
    for (int i = threadIdx.x; i < 16384; i += 1024) kb[i] = s[i];
}

// ------------------------- emit keypoints + scores (fp32) ------------------
__global__ void emit_k(const unsigned long long* __restrict__ keys,
                       float* __restrict__ kp, float* __restrict__ sc)
{
    int tid = blockIdx.x * 256 + threadIdx.x;      // 4 * 4096
    int b = tid >> 12;
    int r = tid & 4095;
    unsigned long long key = keys[(size_t)b * 16384 + r];
    unsigned idx = (unsigned)(key & 0xFFFFFFFFu);
    unsigned hi  = (unsigned)(key >> 32);
    unsigned sk  = ~hi;
    unsigned u   = (sk & 0x80000000u) ? (sk ^ 0x80000000u) : ~sk;
    float val = __uint_as_float(u);
    float tx = (float)(idx % 96);
    float ty = (float)(idx / 96);
    kp[(size_t)tid * 2 + 0] = tx;
    kp[(size_t)tid * 2 + 1] = ty;
    sc[tid] = val;
}

// --------------------- descriptor gather + L2 normalize (fp32) -------------
__global__ __launch_bounds__(256) void desc_out_k(const unsigned long long* __restrict__ keys,
                                                  const float* __restrict__ dm,
                                                  float* __restrict__ outd)
{
    int warp = threadIdx.x >> 6, lane = threadIdx.x & 63;
    int kpid = blockIdx.x * 4 + warp;              // 0..16383
    int b = kpid >> 12, r = kpid & 4095;
    unsigned long long key = keys[(size_t)b * 16384 + r];
    int idx = (int)(unsigned)(key & 0xFFFFFFFFu);
    float v = dm[((size_t)b * 64 + lane) * 9216 + idx];
    float ss = v * v;
#pragma unroll
    for (int o = 32; o > 0; o >>= 1) ss += __shfl_xor(ss, o, 64);
    float n = fmaxf(sqrtf(ss), 1e-12f);
    outd[(size_t)kpid * 64 + lane] = v / n;
}

// ---------------------------------------------------------------------------
extern "C" void kernel_launch(void* const* d_in, const int* in_sizes, int n_in,
                              void* d_out, int out_size, void* d_ws, size_t ws_size,
                              hipStream_t stream)
{
    const float* x      = (const float*)d_in[0];
    const float* w1     = (const float*)d_in[1];
    const float* g1     = (const float*)d_in[2];
    const float* b1     = (const float*)d_in[3];
    const float* w2     = (const float*)d_in[4];
    const float* g2     = (const float*)d_in[5];
    const float* b2     = (const float*)d_in[6];
    const float* w3     = (const float*)d_in[7];
    const float* g3     = (const float*)d_in[8];
    const float* b3     = (const float*)d_in[9];
    const float* w4     = (const float*)d_in[10];
    const float* g4     = (const float*)d_in[11];
    const float* b4     = (const float*)d_in[12];
    const float* wf     = (const float*)d_in[13];
    const float* bf     = (const float*)d_in[14];
    const float* det_w1 = (const float*)d_in[15];
    const float* det_b1 = (const float*)d_in[16];
    const float* det_g  = (const float*)d_in[17];
    const float* det_be = (const float*)d_in[18];
    const float* det_w2 = (const float*)d_in[19];
    const float* det_b2 = (const float*)d_in[20];
    const float* ds_w1  = (const float*)d_in[21];
    const float* ds_b1  = (const float*)d_in[22];
    const float* ds_g1  = (const float*)d_in[23];
    const float* ds_be1 = (const float*)d_in[24];
    const float* ds_w2  = (const float*)d_in[25];
    const float* ds_b2  = (const float*)d_in[26];
    const float* ds_g2  = (const float*)d_in[27];
    const float* ds_be2 = (const float*)d_in[28];

    char* ws = (char*)d_ws;
    // ---- misc persistent buffers at base [0, 819,968) ----
    float* scorem = (float*)(ws + 0);                              // [4,9216]
    unsigned long long* keys = (unsigned long long*)(ws + 147456); // [4,16384]
    float* wc  = (float*)(ws + 671744);                            // [64,64,9]
    float* pc  = (float*)(ws + 819200);                            // 768 B
    float* cbc = pc, *gc = pc + 64, *bec = pc + 128;
    const size_t B0 = 819968;

    pack_head_k<<<72, 256, 0, stream>>>(det_w1, det_b1, det_g, det_be,
                                        ds_w1, ds_b1, ds_g1, ds_be1,
                                        wc, cbc, gc, bec);

    float* desc_full;

    if (ws_size >= 59200000ull) {
        // =============== Layout A (peak 59,028,224 B) ======================
        float* c1pb  = (float*)(ws + B0);           // [32,386,386]   (phase 1)
        float* c2p   = (float*)(ws + 20488960);     // [4,64,194,194]
        float* c3p   = (float*)(ws + B0);           // [4,128,98,98]  (phase 2)
        float* c4    = (float*)(ws + 20488960);     // [4,256,96,96]  (phase 3)
        float* featp = (float*)(ws + B0);           // [4,64,98,98]   (phase 4)
        float* dd1   = (float*)(ws + 10654464);     // [4,64,96,96]
        desc_full    = (float*)(ws + 20488960);     // [4,64,96,96]

        zero_k<<<2048, 256, 0, stream>>>((float4*)(ws + B0), 3638016);

        for (int b = 0; b < 4; b++) {
            conv3x3b_k<3, 32, 4, 3, 384, 2, 1, 4, 1, 1, 1><<<96 * 8, 384, 0, stream>>>(
                x + (size_t)b * 3 * 768 * 768, w1, nullptr, g1, b1, c1pb);
            conv3x3p_k<32, 64, 4, 32, 192, 2, 1, 4, 1, 1, 1><<<48 * 16, 192, 0, stream>>>(
                c1pb, w2, nullptr, g2, b2, c2p + (size_t)b * 2408704);
        }
        zero_k<<<2048, 256, 0, stream>>>((float4*)(ws + B0), 1229312);
        conv3x3p_k<64, 128, 4, 32, 96, 2, 2, 4, 1, 1, 1><<<12 * 32 * 4, 192, 0, stream>>>(
            c2p, w3, nullptr, g3, b3, c3p);
        conv3x3p_k<128, 256, 4, 32, 96, 1, 2, 4, 1, 1, 0><<<12 * 64 * 4, 192, 0, stream>>>(
            c3p, w4, nullptr, g4, b4, c4);
        zero_k<<<2048, 256, 0, stream>>>((float4*)(ws + B0), 614656);
        conv1x1p_k<256, 64, 8, 64, 2, 4, 0, 0, 1><<<12 * 8 * 4, 192, 0, stream>>>(
            c4, wf, bf, nullptr, nullptr, featp, 256, 0);
        conv3x3p_k<64, 64, 4, 32, 96, 1, 2, 4, 1, 1, 0><<<12 * 16 * 4, 192, 0, stream>>>(
            featp, wc, cbc, gc, bec, dd1);
        conv1x1p_k<32, 1, 1, 32, 2, 4, 0, 0, 0><<<12 * 1 * 4, 192, 0, stream>>>(
            dd1, det_w2, det_b2, nullptr, nullptr, scorem, 64, 0);
        conv1x1p_k<32, 64, 8, 32, 2, 4, 0, 1, 0><<<12 * 8 * 4, 192, 0, stream>>>(
            dd1, ds_w2, ds_b2, ds_g2, ds_be2, desc_full, 64, 32);
    } else {
        // =============== Layout B (peak 57,443,072 B) ======================
        float* c3    = (float*)(ws + B0);           // [4,128,96,96] unpadded
        float* c1pb  = (float*)(ws + 19694336);     // [32,386,386]
        float* c2pb  = (float*)(ws + 38765824);     // [64,194,194]
        float* c4    = (float*)(ws + 19694336);     // [4,256,96,96]
        float* featp = (float*)(ws + B0);           // [4,64,98,98]
        float* dd1   = (float*)(ws + 10654464);     // [4,64,96,96]
        desc_full    = (float*)(ws + 20091648);     // [4,64,96,96]

        zero_k<<<2048, 256, 0, stream>>>((float4*)(ws + B0), 2973792);

        for (int b = 0; b < 4; b++) {
            conv3x3b_k<3, 32, 4, 3, 384, 2, 1, 4, 1, 1, 1><<<96 * 8, 384, 0, stream>>>(
                x + (size_t)b * 3 * 768 * 768, w1, nullptr, g1, b1, c1pb);
            conv3x3p_k<32, 64, 4, 32, 192, 2, 1, 4, 1, 1, 1><<<48 * 16, 192, 0, stream>>>(
                c1pb, w2, nullptr, g2, b2, c2pb);
            conv3x3p_k<64, 128, 4, 32, 96, 2, 2, 4, 1, 1, 0><<<12 * 32, 192, 0, stream>>>(
                c2pb, w3, nullptr, g3, b3, c3 + (size_t)b * 1179648);
        }
        conv3x3b_k<128, 256, 4, 32, 96, 1, 2, 4, 1, 1, 0><<<12 * 64 * 4, 192, 0, stream>>>(
            c3, w4, nullptr, g4, b4, c4);
        zero_k<<<2048, 256, 0, stream>>>((float4*)(ws + B0), 614656);
        conv1x1p_k<256, 64, 8, 64, 2, 4, 0, 0, 1><<<12 * 8 * 4, 192, 0, stream>>>(
            c4, wf, bf, nullptr, nullptr, featp, 256, 0);
        conv3x3p_k<64, 64, 4, 32, 96, 1, 2, 4, 1, 1, 0><<<12 * 16 * 4, 192, 0, stream>>>(
            featp, wc, cbc, gc, bec, dd1);
        conv1x1p_k<32, 1, 1, 32, 2, 4, 0, 0, 0><<<12 * 1 * 4, 192, 0, stream>>>(
            dd1, det_w2, det_b2, nullptr, nullptr, scorem, 64, 0);
        conv1x1p_k<32, 64, 8, 32, 2, 4, 0, 1, 0><<<12 * 8 * 4, 192, 0, stream>>>(
            dd1, ds_w2, ds_b2, ds_g2, ds_be2, desc_full, 64, 32);
    }

    nms_keys_k<<<256, 256, 0, stream>>>(scorem, keys);
    sort_k<<<4, 1024, 0, stream>>>(keys);

    float* out_kp = (float*)d_out;
    float* out_sc = out_kp + 4 * 4096 * 2;
    float* out_d  = out_sc + 4 * 4096;
    emit_k<<<64, 256, 0, stream>>>(keys, out_kp, out_sc);
    desc_out_k<<<4096, 256, 0, stream>>>(keys, desc_full, out_d);
}